// Round 2
// baseline (1259.673 us; speedup 1.0000x reference)
//
#include <hip/hip_runtime.h>
#include <hip/hip_bf16.h>

// Problem constants
#define BB 4
#define NCC 1792
#define NTT 256
#define NN 2048        // NCC + NTT
#define DMv 256
#define DIv 512
#define DSv 16
#define DTRv 16
#define KK 4
#define LL 4
#define NTOK (BB*NN)   // 8192

#define CCH 64         // chunks for scan
#define CL  32         // chunk length = NN/CCH

__device__ __forceinline__ float siluf(float x) {
    return x / (1.f + expf(-x));
}
__device__ __forceinline__ float softplusf(float x) {
    return fmaxf(x, 0.f) + log1pf(expf(-fabsf(x)));
}

// ---------------------------------------------------------------------------
// Embed phase 1: h1 = relu(x*We1[0,:] + yprev*We1[1,:] + be1)  (rank-2)
// ---------------------------------------------------------------------------
__global__ __launch_bounds__(256) void embed_h1_kernel(
    const float* __restrict__ xc, const float* __restrict__ yc,
    const float* __restrict__ xt, const float* __restrict__ yt,
    const float* __restrict__ We1, const float* __restrict__ be1,
    float* __restrict__ h1)
{
    int token = blockIdx.x;
    int b = token >> 11, t = token & (NN - 1);
    int d = threadIdx.x;

    float xv = (t < NCC) ? xc[b*NCC + t] : xt[b*NTT + (t - NCC)];
    float yp = 0.f;
    if (t > 0) {
        int tp = t - 1;
        yp = (tp < NCC) ? yc[b*NCC + tp] : yt[b*NTT + (tp - NCC)];
    }
    float h = fmaf(xv, We1[d], fmaf(yp, We1[DMv + d], be1[d]));
    h1[(long)token*DMv + d] = fmaxf(h, 0.f);
}

// ---------------------------------------------------------------------------
// rinv[token] = rsqrt(mean(z^2) + 1e-5): 4 tokens per 256-thread block
// ---------------------------------------------------------------------------
__global__ __launch_bounds__(256) void rinv_kernel(
    const float* __restrict__ z, float* __restrict__ rinv)
{
    int tid = threadIdx.x;
    int token = blockIdx.x*4 + (tid >> 6);
    int lane = tid & 63;
    float4 v = *(const float4*)&z[(long)token*DMv + lane*4];
    float ss = v.x*v.x + v.y*v.y + v.z*v.z + v.w*v.w;
    #pragma unroll
    for (int m = 32; m >= 1; m >>= 1) ss += __shfl_xor(ss, m, 64);
    if (lane == 0) rinv[token] = rsqrtf(ss * (1.f/DMv) + 1e-5f);
}

// ---------------------------------------------------------------------------
// fp32 GEMM: C[M,N] = op(A)[M,K] @ B[K,N]  (+C if RES, +bias if BIAS)
// NORM: A element (m,k) scaled by rinv[m]*nw[k] (fused RMSNorm)
// ---------------------------------------------------------------------------
template<int BM, int BN, int BK, int TM, int TN, bool NORM, bool RES, bool BIAS>
__global__ __launch_bounds__(256, 2) void gemm_k(
    const float* __restrict__ A, const float* __restrict__ B,
    float* __restrict__ Cmat,
    const float* __restrict__ rinv, const float* __restrict__ nw,
    const float* __restrict__ bias,
    int M, int N, int K)
{
    constexpr int TX = BN / TN;
    constexpr int TY = BM / TM;
    static_assert(TX * TY == 256, "bad cfg");

    __shared__ float As[BK][BM + 4];
    __shared__ float Bs[BK][BN + 4];

    int tid = threadIdx.x;
    int tx = tid % TX, ty = tid / TX;
    int bm0 = blockIdx.y * BM, bn0 = blockIdx.x * BN;

    float acc[TM][TN];
    #pragma unroll
    for (int i = 0; i < TM; i++)
        #pragma unroll
        for (int j = 0; j < TN; j++) acc[i][j] = 0.f;

    for (int k0 = 0; k0 < K; k0 += BK) {
        // A tile BMxBK -> As[k][m] (transposed), optional rmsnorm scaling
        #pragma unroll
        for (int i = 0; i < BM*BK/(4*256); i++) {
            int idx4 = tid + i*256;
            int m  = idx4 / (BK/4);
            int k4 = idx4 % (BK/4);
            float4 v = *(const float4*)&A[(long)(bm0 + m)*K + k0 + k4*4];
            if (NORM) {
                float s = rinv[bm0 + m];
                float4 nv = *(const float4*)&nw[k0 + k4*4];
                v.x *= s*nv.x; v.y *= s*nv.y; v.z *= s*nv.z; v.w *= s*nv.w;
            }
            As[k4*4+0][m] = v.x; As[k4*4+1][m] = v.y;
            As[k4*4+2][m] = v.z; As[k4*4+3][m] = v.w;
        }
        // B tile BKxBN
        #pragma unroll
        for (int i = 0; i < BK*BN/(4*256); i++) {
            int idx4 = tid + i*256;
            int k  = idx4 / (BN/4);
            int n4 = idx4 % (BN/4);
            *(float4*)&Bs[k][n4*4] = *(const float4*)&B[(long)(k0 + k)*N + bn0 + n4*4];
        }
        __syncthreads();

        #pragma unroll
        for (int k = 0; k < BK; k++) {
            float a[TM], bb[TN];
            #pragma unroll
            for (int i = 0; i < TM; i += 4) {
                float4 v = *(const float4*)&As[k][ty*TM + i];
                a[i] = v.x; a[i+1] = v.y; a[i+2] = v.z; a[i+3] = v.w;
            }
            #pragma unroll
            for (int j = 0; j < TN; j += 4) {
                float4 v = *(const float4*)&Bs[k][tx*TN + j];
                bb[j] = v.x; bb[j+1] = v.y; bb[j+2] = v.z; bb[j+3] = v.w;
            }
            #pragma unroll
            for (int i = 0; i < TM; i++)
                #pragma unroll
                for (int j = 0; j < TN; j++)
                    acc[i][j] = fmaf(a[i], bb[j], acc[i][j]);
        }
        __syncthreads();
    }

    #pragma unroll
    for (int i = 0; i < TM; i++) {
        #pragma unroll
        for (int j = 0; j < TN; j += 4) {
            long off = (long)(bm0 + ty*TM + i)*N + bn0 + tx*TN + j;
            float4 v;
            v.x = acc[i][j]; v.y = acc[i][j+1]; v.z = acc[i][j+2]; v.w = acc[i][j+3];
            if (BIAS) {
                float4 bv = *(const float4*)&bias[bn0 + tx*TN + j];
                v.x += bv.x; v.y += bv.y; v.z += bv.z; v.w += bv.w;
            }
            if (RES) {
                float4 r = *(const float4*)&Cmat[off];
                v.x += r.x; v.y += r.y; v.z += r.z; v.w += r.w;
            }
            *(float4*)&Cmat[off] = v;
        }
    }
}

// ---------------------------------------------------------------------------
// Fused: depthwise causal conv(K=4)+bias+SiLU -> uc ; uc@Wx (512->48) ;
// delta = softplus(dt@Wdt + bdt). One 256-thread block per token.
// ---------------------------------------------------------------------------
__global__ __launch_bounds__(256) void conv_proj_kernel(
    const float* __restrict__ ug, const float* __restrict__ Wc,
    const float* __restrict__ bcv, const float* __restrict__ Wx,
    const float* __restrict__ Wdt, const float* __restrict__ bdt,
    float* __restrict__ uc, float* __restrict__ bc2, float* __restrict__ delta)
{
    int token = blockIdx.x;
    int t = token & (NN - 1);
    int tid = threadIdx.x;
    __shared__ float us[DIv];
    __shared__ float dts[DTRv];

    // phase 1: conv + silu (2 channels per thread)
    #pragma unroll
    for (int r = 0; r < 2; r++) {
        int di = tid + r*256;
        float acc = bcv[di];
        #pragma unroll
        for (int j = 0; j < KK; j++) {
            int tt = t - 3 + j;
            if (tt >= 0)
                acc = fmaf(ug[((long)(token - 3 + j) << 10) + di], Wc[di*KK + j], acc);
        }
        float u = siluf(acc);
        us[di] = u;
        uc[(long)token*DIv + di] = u;
    }
    __syncthreads();

    // phase 2: 48 dots of length 512 (4 lanes each)
    int o = tid >> 2, sub = tid & 3;
    if (o < 48) {
        float acc = 0.f;
        int kk0 = sub * 128;
        #pragma unroll 8
        for (int k = 0; k < 128; k++)
            acc = fmaf(us[kk0 + k], Wx[(long)(kk0 + k)*48 + o], acc);
        acc += __shfl_xor(acc, 1, 64);
        acc += __shfl_xor(acc, 2, 64);
        if (sub == 0) {
            if (o < DTRv) dts[o] = acc;
            else bc2[(long)token*32 + (o - DTRv)] = acc;
        }
    }
    __syncthreads();

    // phase 3: delta = softplus(dts@Wdt + bdt)
    #pragma unroll
    for (int r = 0; r < 2; r++) {
        int di = tid + r*256;
        float a = bdt[di];
        #pragma unroll
        for (int k = 0; k < DTRv; k++) a = fmaf(dts[k], Wdt[k*DIv + di], a);
        delta[(long)token*DIv + di] = softplusf(a);
    }
}

// ---------------------------------------------------------------------------
// Scan pass A: per-chunk local scan (h=0) -> decay product P, final h
// ---------------------------------------------------------------------------
__global__ __launch_bounds__(256) void scanA_kernel(
    const float* __restrict__ delta, const float* __restrict__ uc,
    const float* __restrict__ bc2, const float* __restrict__ Alog,
    float* __restrict__ Pbuf, float* __restrict__ hfin)
{
    int half = blockIdx.x, c = blockIdx.y, b = blockIdx.z;
    int di = half*256 + threadIdx.x;

    float A[DSv], h[DSv], P[DSv];
    #pragma unroll
    for (int s = 0; s < DSv; s++) {
        A[s] = -expf(Alog[di*DSv + s]);
        h[s] = 0.f; P[s] = 1.f;
    }

    __shared__ float Bsh[CL][DSv];
    int t0 = c * CL;
    for (int i = threadIdx.x; i < CL*DSv; i += 256) {
        int tt = i >> 4, s = i & 15;
        Bsh[tt][s] = bc2[((long)(b*NN + t0 + tt))*32 + s];
    }
    __syncthreads();

    for (int tt = 0; tt < CL; tt++) {
        long token = (long)b*NN + t0 + tt;
        float d  = delta[token*DIv + di];
        float du = d * uc[token*DIv + di];
        #pragma unroll
        for (int s = 0; s < DSv; s++) {
            float a = expf(d * A[s]);
            P[s] *= a;
            h[s] = fmaf(a, h[s], du * Bsh[tt][s]);
        }
    }
    long base = (((long)c*BB + b)*DIv + di)*DSv;
    #pragma unroll
    for (int s = 0; s < DSv; s++) { Pbuf[base+s] = P[s]; hfin[base+s] = h[s]; }
}

// ---------------------------------------------------------------------------
// Scan pass B: sequential over chunks; Pbuf is overwritten with chunk-initial
// states (aliased Hinit).
// ---------------------------------------------------------------------------
__global__ __launch_bounds__(256) void scanB_kernel(
    float* __restrict__ Pbuf, const float* __restrict__ hfin)
{
    int id = blockIdx.x * 256 + threadIdx.x;  // (b*512+di)*16+s
    float H = 0.f;
    for (int c = 0; c < CCH; c++) {
        long idx = (long)c * (BB*DIv*DSv) + id;
        float p  = Pbuf[idx];
        float hf = hfin[idx];
        Pbuf[idx] = H;               // becomes Hinit
        H = fmaf(p, H, hf);
    }
}

// ---------------------------------------------------------------------------
// Scan pass C + gate: re-scan with correct init; yg = (y + D*u)*silu(gate)
// written IN PLACE into delta (each element read-then-written by one thread).
// ---------------------------------------------------------------------------
__global__ __launch_bounds__(256) void scanC_gate_kernel(
    float* __restrict__ delta, const float* __restrict__ uc,
    const float* __restrict__ bc2, const float* __restrict__ Alog,
    const float* __restrict__ Hinit, const float* __restrict__ ug,
    const float* __restrict__ Dp)
{
    int half = blockIdx.x, c = blockIdx.y, b = blockIdx.z;
    int di = half*256 + threadIdx.x;

    float A[DSv], h[DSv];
    long base = (((long)c*BB + b)*DIv + di)*DSv;
    #pragma unroll
    for (int s = 0; s < DSv; s++) {
        A[s] = -expf(Alog[di*DSv + s]);
        h[s] = Hinit[base + s];
    }
    float Dv = Dp[di];

    __shared__ float Bsh[CL][DSv];
    __shared__ float Csh[CL][DSv];
    int t0 = c * CL;
    for (int i = threadIdx.x; i < CL*DSv; i += 256) {
        int tt = i >> 4, s = i & 15;
        long tok = (long)(b*NN + t0 + tt) * 32;
        Bsh[tt][s] = bc2[tok + s];
        Csh[tt][s] = bc2[tok + DSv + s];
    }
    __syncthreads();

    for (int tt = 0; tt < CL; tt++) {
        long token = (long)b*NN + t0 + tt;
        float d   = delta[token*DIv + di];
        float ucv = uc[token*DIv + di];
        float du  = d * ucv;
        float y = 0.f;
        #pragma unroll
        for (int s = 0; s < DSv; s++) {
            float a = expf(d * A[s]);
            h[s] = fmaf(a, h[s], du * Bsh[tt][s]);
            y = fmaf(h[s], Csh[tt][s], y);
        }
        float gq = ug[((long)token << 10) + DIv + di];
        delta[token*DIv + di] = fmaf(Dv, ucv, y) * siluf(gq);
    }
}

// ---------------------------------------------------------------------------
extern "C" void kernel_launch(void* const* d_in, const int* in_sizes, int n_in,
                              void* d_out, int out_size, void* d_ws, size_t ws_size,
                              hipStream_t stream)
{
    const float* xc     = (const float*)d_in[0];
    const float* yc     = (const float*)d_in[1];
    const float* xt     = (const float*)d_in[2];
    const float* yt     = (const float*)d_in[3];
    const float* We1    = (const float*)d_in[4];
    const float* be1    = (const float*)d_in[5];
    const float* We2    = (const float*)d_in[6];
    const float* be2    = (const float*)d_in[7];
    const float* norm_w = (const float*)d_in[8];
    const float* W_in   = (const float*)d_in[9];
    const float* W_conv = (const float*)d_in[10];
    const float* b_conv = (const float*)d_in[11];
    const float* W_xproj= (const float*)d_in[12];
    const float* W_dt   = (const float*)d_in[13];
    const float* b_dt   = (const float*)d_in[14];
    const float* A_log  = (const float*)d_in[15];
    const float* Dp     = (const float*)d_in[16];
    const float* W_out  = (const float*)d_in[17];

    float* z  = (float*)d_out;               // (B,N,DM) in place
    float* ws = (float*)d_ws;

    float* ug    = ws;                        // NTOK*1024 (also embed h1)
    float* uc    = ug    + (long)NTOK*2*DIv;  // NTOK*512
    float* delta = uc    + (long)NTOK*DIv;    // NTOK*512 (becomes yg in scanC)
    float* bc2   = delta + (long)NTOK*DIv;    // NTOK*32
    float* rinv  = bc2   + (long)NTOK*32;     // NTOK
    float* Pbuf  = rinv  + NTOK;              // CCH*BB*DIv*DSv (also Hinit)
    float* hfin  = Pbuf  + (long)CCH*BB*DIv*DSv;

    float* h1 = ug;  // alias: embed h1 lives in ug region until first gemm_in

    embed_h1_kernel<<<NTOK, 256, 0, stream>>>(xc, yc, xt, yt, We1, be1, h1);
    // z = h1 @ We2 + be2
    gemm_k<32,128,32,4,4,false,false,true><<<dim3(DMv/128, NTOK/32), 256, 0, stream>>>(
        h1, We2, z, nullptr, nullptr, be2, NTOK, DMv, DMv);

    for (int l = 0; l < LL; l++) {
        rinv_kernel<<<NTOK/4, 256, 0, stream>>>(z, rinv);

        // ug = rmsnorm(z) @ W_in
        gemm_k<128,128,32,8,8,true,false,false><<<dim3(2*DIv/128, NTOK/128), 256, 0, stream>>>(
            z, W_in + (long)l*DMv*2*DIv, ug, rinv, norm_w + l*DMv, nullptr,
            NTOK, 2*DIv, DMv);

        conv_proj_kernel<<<NTOK, 256, 0, stream>>>(
            ug, W_conv + l*DIv*KK, b_conv + l*DIv,
            W_xproj + (long)l*DIv*(DTRv+2*DSv), W_dt + l*DTRv*DIv, b_dt + l*DIv,
            uc, bc2, delta);

        scanA_kernel<<<dim3(2, CCH, BB), 256, 0, stream>>>(
            delta, uc, bc2, A_log + (long)l*DIv*DSv, Pbuf, hfin);

        scanB_kernel<<<BB*DIv*DSv/256, 256, 0, stream>>>(Pbuf, hfin);

        scanC_gate_kernel<<<dim3(2, CCH, BB), 256, 0, stream>>>(
            delta, uc, bc2, A_log + (long)l*DIv*DSv, Pbuf, ug, Dp + l*DIv);

        // z += yg @ W_out   (yg lives in delta)
        gemm_k<32,128,32,4,4,false,true,false><<<dim3(DMv/128, NTOK/32), 256, 0, stream>>>(
            delta, W_out + (long)l*DIv*DMv, z, nullptr, nullptr, nullptr,
            NTOK, DMv, DIv);
    }
}

// Round 3
// 1035.522 us; speedup vs baseline: 1.2165x; 1.2165x over previous
//
#include <hip/hip_runtime.h>
#include <hip/hip_bf16.h>

// Problem constants
#define BB 4
#define NCC 1792
#define NTT 256
#define NN 2048        // NCC + NTT
#define DMv 256
#define DIv 512
#define DSv 16
#define DTRv 16
#define KK 4
#define LL 4
#define NTOK (BB*NN)   // 8192

#define CCH 64         // chunks for scan
#define CL  32         // chunk length = NN/CCH

__device__ __forceinline__ float siluf(float x) {
    return x / (1.f + expf(-x));
}
__device__ __forceinline__ float softplusf(float x) {
    return fmaxf(x, 0.f) + log1pf(expf(-fabsf(x)));
}

// ---------------------------------------------------------------------------
// Embed phase 1: h1 = relu(x*We1[0,:] + yprev*We1[1,:] + be1)  (rank-2)
// ---------------------------------------------------------------------------
__global__ __launch_bounds__(256) void embed_h1_kernel(
    const float* __restrict__ xc, const float* __restrict__ yc,
    const float* __restrict__ xt, const float* __restrict__ yt,
    const float* __restrict__ We1, const float* __restrict__ be1,
    float* __restrict__ h1)
{
    int token = blockIdx.x;
    int b = token >> 11, t = token & (NN - 1);
    int d = threadIdx.x;

    float xv = (t < NCC) ? xc[b*NCC + t] : xt[b*NTT + (t - NCC)];
    float yp = 0.f;
    if (t > 0) {
        int tp = t - 1;
        yp = (tp < NCC) ? yc[b*NCC + tp] : yt[b*NTT + (tp - NCC)];
    }
    float h = fmaf(xv, We1[d], fmaf(yp, We1[DMv + d], be1[d]));
    h1[(long)token*DMv + d] = fmaxf(h, 0.f);
}

// ---------------------------------------------------------------------------
// rinv[token] = rsqrt(mean(z^2) + 1e-5): 4 tokens per 256-thread block
// ---------------------------------------------------------------------------
__global__ __launch_bounds__(256) void rinv_kernel(
    const float* __restrict__ z, float* __restrict__ rinv)
{
    int tid = threadIdx.x;
    int token = blockIdx.x*4 + (tid >> 6);
    int lane = tid & 63;
    float4 v = *(const float4*)&z[(long)token*DMv + lane*4];
    float ss = v.x*v.x + v.y*v.y + v.z*v.z + v.w*v.w;
    #pragma unroll
    for (int m = 32; m >= 1; m >>= 1) ss += __shfl_xor(ss, m, 64);
    if (lane == 0) rinv[token] = rsqrtf(ss * (1.f/DMv) + 1e-5f);
}

// ---------------------------------------------------------------------------
// Pad W_xproj (L,512,48) -> Wxpad (L,512,64), zero columns 48..63
// ---------------------------------------------------------------------------
__global__ __launch_bounds__(256) void pad_wx_kernel(
    const float* __restrict__ Wx, float* __restrict__ Wxpad)
{
    int idx = blockIdx.x*256 + threadIdx.x;       // L*512*64 total
    int o = idx & 63;
    int lk = idx >> 6;                            // l*512 + k
    Wxpad[idx] = (o < 48) ? Wx[lk*48 + o] : 0.f;
}

// ---------------------------------------------------------------------------
// fp32 GEMM: C[M,N] = op(A)[M,K] @ B[K,N]  (+C if RES, +bias if BIAS)
// NORM: A element (m,k) scaled by rinv[m]*nw[k] (fused RMSNorm)
// ---------------------------------------------------------------------------
template<int BM, int BN, int BK, int TM, int TN, bool NORM, bool RES, bool BIAS>
__global__ __launch_bounds__(256, 2) void gemm_k(
    const float* __restrict__ A, const float* __restrict__ B,
    float* __restrict__ Cmat,
    const float* __restrict__ rinv, const float* __restrict__ nw,
    const float* __restrict__ bias,
    int M, int N, int K)
{
    constexpr int TX = BN / TN;
    constexpr int TY = BM / TM;
    static_assert(TX * TY == 256, "bad cfg");
    static_assert((BM*BK) % (4*256) == 0 && (BK*BN) % (4*256) == 0, "bad loader");

    __shared__ float As[BK][BM + 4];
    __shared__ float Bs[BK][BN + 4];

    int tid = threadIdx.x;
    int tx = tid % TX, ty = tid / TX;
    int bm0 = blockIdx.y * BM, bn0 = blockIdx.x * BN;

    float acc[TM][TN];
    #pragma unroll
    for (int i = 0; i < TM; i++)
        #pragma unroll
        for (int j = 0; j < TN; j++) acc[i][j] = 0.f;

    for (int k0 = 0; k0 < K; k0 += BK) {
        #pragma unroll
        for (int i = 0; i < BM*BK/(4*256); i++) {
            int idx4 = tid + i*256;
            int m  = idx4 / (BK/4);
            int k4 = idx4 % (BK/4);
            float4 v = *(const float4*)&A[(long)(bm0 + m)*K + k0 + k4*4];
            if (NORM) {
                float s = rinv[bm0 + m];
                float4 nv = *(const float4*)&nw[k0 + k4*4];
                v.x *= s*nv.x; v.y *= s*nv.y; v.z *= s*nv.z; v.w *= s*nv.w;
            }
            As[k4*4+0][m] = v.x; As[k4*4+1][m] = v.y;
            As[k4*4+2][m] = v.z; As[k4*4+3][m] = v.w;
        }
        #pragma unroll
        for (int i = 0; i < BK*BN/(4*256); i++) {
            int idx4 = tid + i*256;
            int k  = idx4 / (BN/4);
            int n4 = idx4 % (BN/4);
            *(float4*)&Bs[k][n4*4] = *(const float4*)&B[(long)(k0 + k)*N + bn0 + n4*4];
        }
        __syncthreads();

        #pragma unroll
        for (int k = 0; k < BK; k++) {
            float a[TM], bb[TN];
            #pragma unroll
            for (int i = 0; i < TM; i += 4) {
                float4 v = *(const float4*)&As[k][ty*TM + i];
                a[i] = v.x; a[i+1] = v.y; a[i+2] = v.z; a[i+3] = v.w;
            }
            #pragma unroll
            for (int j = 0; j < TN; j += 4) {
                float4 v = *(const float4*)&Bs[k][tx*TN + j];
                bb[j] = v.x; bb[j+1] = v.y; bb[j+2] = v.z; bb[j+3] = v.w;
            }
            #pragma unroll
            for (int i = 0; i < TM; i++)
                #pragma unroll
                for (int j = 0; j < TN; j++)
                    acc[i][j] = fmaf(a[i], bb[j], acc[i][j]);
        }
        __syncthreads();
    }

    #pragma unroll
    for (int i = 0; i < TM; i++) {
        #pragma unroll
        for (int j = 0; j < TN; j += 4) {
            long off = (long)(bm0 + ty*TM + i)*N + bn0 + tx*TN + j;
            float4 v;
            v.x = acc[i][j]; v.y = acc[i][j+1]; v.z = acc[i][j+2]; v.w = acc[i][j+3];
            if (BIAS) {
                float4 bv = *(const float4*)&bias[bn0 + tx*TN + j];
                v.x += bv.x; v.y += bv.y; v.z += bv.z; v.w += bv.w;
            }
            if (RES) {
                float4 r = *(const float4*)&Cmat[off];
                v.x += r.x; v.y += r.y; v.z += r.z; v.w += r.w;
            }
            *(float4*)&Cmat[off] = v;
        }
    }
}

// ---------------------------------------------------------------------------
// Depthwise causal conv(K=4)+bias+SiLU, vectorized: thread = (token, 4 chans)
// ---------------------------------------------------------------------------
__global__ __launch_bounds__(256) void conv_silu_kernel(
    const float* __restrict__ ug, const float* __restrict__ Wc,
    const float* __restrict__ bcv, float* __restrict__ uc)
{
    int idx = blockIdx.x*256 + threadIdx.x;       // NTOK * DIv/4
    int di = (idx & (DIv/4 - 1)) * 4;
    int token = idx >> 7;
    int t = token & (NN - 1);

    float4 w0 = *(const float4*)&Wc[(di+0)*KK];   // taps of chan di
    float4 w1 = *(const float4*)&Wc[(di+1)*KK];
    float4 w2 = *(const float4*)&Wc[(di+2)*KK];
    float4 w3 = *(const float4*)&Wc[(di+3)*KK];
    float4 acc = *(const float4*)&bcv[di];

    float4 u;
    if (t >= 3) {
        u = *(const float4*)&ug[((long)(token-3) << 10) + di];
        acc.x = fmaf(u.x, w0.x, acc.x); acc.y = fmaf(u.y, w1.x, acc.y);
        acc.z = fmaf(u.z, w2.x, acc.z); acc.w = fmaf(u.w, w3.x, acc.w);
    }
    if (t >= 2) {
        u = *(const float4*)&ug[((long)(token-2) << 10) + di];
        acc.x = fmaf(u.x, w0.y, acc.x); acc.y = fmaf(u.y, w1.y, acc.y);
        acc.z = fmaf(u.z, w2.y, acc.z); acc.w = fmaf(u.w, w3.y, acc.w);
    }
    if (t >= 1) {
        u = *(const float4*)&ug[((long)(token-1) << 10) + di];
        acc.x = fmaf(u.x, w0.z, acc.x); acc.y = fmaf(u.y, w1.z, acc.y);
        acc.z = fmaf(u.z, w2.z, acc.z); acc.w = fmaf(u.w, w3.z, acc.w);
    }
    u = *(const float4*)&ug[((long)token << 10) + di];
    acc.x = fmaf(u.x, w0.w, acc.x); acc.y = fmaf(u.y, w1.w, acc.y);
    acc.z = fmaf(u.z, w2.w, acc.z); acc.w = fmaf(u.w, w3.w, acc.w);

    acc.x = siluf(acc.x); acc.y = siluf(acc.y);
    acc.z = siluf(acc.z); acc.w = siluf(acc.w);
    *(float4*)&uc[(long)token*DIv + di] = acc;
}

// ---------------------------------------------------------------------------
// Scan pass A: per-chunk local scan (h=0) -> decay product P, final h
// delta computed on the fly from dt (dbl cols 0..15) @ Wdt + bdt
// ---------------------------------------------------------------------------
__global__ __launch_bounds__(256) void scanA_kernel(
    const float* __restrict__ dbl, const float* __restrict__ uc,
    const float* __restrict__ Alog, const float* __restrict__ Wdt,
    const float* __restrict__ bdt,
    float* __restrict__ Pbuf, float* __restrict__ hfin)
{
    int half = blockIdx.x, c = blockIdx.y, b = blockIdx.z;
    int di = half*256 + threadIdx.x;

    float A[DSv], h[DSv], P[DSv], wdt[DTRv];
    #pragma unroll
    for (int s = 0; s < DSv; s++) {
        A[s] = -expf(Alog[di*DSv + s]);
        h[s] = 0.f; P[s] = 1.f;
    }
    #pragma unroll
    for (int k = 0; k < DTRv; k++) wdt[k] = Wdt[k*DIv + di];
    float bdtv = bdt[di];

    __shared__ float Dsh[CL][DTRv];
    __shared__ float Bsh[CL][DSv];
    int t0 = c * CL;
    for (int i = threadIdx.x; i < CL*DSv; i += 256) {
        int tt = i >> 4, s = i & 15;
        long row = (long)(b*NN + t0 + tt) * 64;
        Dsh[tt][s] = dbl[row + s];
        Bsh[tt][s] = dbl[row + DTRv + s];
    }
    __syncthreads();

    for (int tt = 0; tt < CL; tt++) {
        long token = (long)b*NN + t0 + tt;
        float dt = bdtv;
        #pragma unroll
        for (int k = 0; k < DTRv; k++) dt = fmaf(Dsh[tt][k], wdt[k], dt);
        float d  = softplusf(dt);
        float du = d * uc[token*DIv + di];
        #pragma unroll
        for (int s = 0; s < DSv; s++) {
            float a = expf(d * A[s]);
            P[s] *= a;
            h[s] = fmaf(a, h[s], du * Bsh[tt][s]);
        }
    }
    long base = (((long)c*BB + b)*DIv + di)*DSv;
    #pragma unroll
    for (int s = 0; s < DSv; s++) { Pbuf[base+s] = P[s]; hfin[base+s] = h[s]; }
}

// ---------------------------------------------------------------------------
// Scan pass B: sequential over chunks; Pbuf overwritten with chunk-initial H
// ---------------------------------------------------------------------------
__global__ __launch_bounds__(256) void scanB_kernel(
    float* __restrict__ Pbuf, const float* __restrict__ hfin)
{
    int id = blockIdx.x * 256 + threadIdx.x;  // (b*512+di)*16+s
    float H = 0.f;
    for (int c = 0; c < CCH; c++) {
        long idx = (long)c * (BB*DIv*DSv) + id;
        float p  = Pbuf[idx];
        float hf = hfin[idx];
        Pbuf[idx] = H;               // becomes Hinit
        H = fmaf(p, H, hf);
    }
}

// ---------------------------------------------------------------------------
// Scan pass C + gate: re-scan with correct init; yg = (y + D*u)*silu(gate)
// written IN PLACE into uc (in-thread read-then-write).
// ---------------------------------------------------------------------------
__global__ __launch_bounds__(256) void scanC_gate_kernel(
    const float* __restrict__ dbl, float* __restrict__ uc,
    const float* __restrict__ Alog, const float* __restrict__ Wdt,
    const float* __restrict__ bdt, const float* __restrict__ Hinit,
    const float* __restrict__ ug, const float* __restrict__ Dp)
{
    int half = blockIdx.x, c = blockIdx.y, b = blockIdx.z;
    int di = half*256 + threadIdx.x;

    float A[DSv], h[DSv], wdt[DTRv];
    long base = (((long)c*BB + b)*DIv + di)*DSv;
    #pragma unroll
    for (int s = 0; s < DSv; s++) {
        A[s] = -expf(Alog[di*DSv + s]);
        h[s] = Hinit[base + s];
    }
    #pragma unroll
    for (int k = 0; k < DTRv; k++) wdt[k] = Wdt[k*DIv + di];
    float bdtv = bdt[di];
    float Dv = Dp[di];

    __shared__ float Dsh[CL][DTRv];
    __shared__ float Bsh[CL][DSv];
    __shared__ float Csh[CL][DSv];
    int t0 = c * CL;
    for (int i = threadIdx.x; i < CL*DSv; i += 256) {
        int tt = i >> 4, s = i & 15;
        long row = (long)(b*NN + t0 + tt) * 64;
        Dsh[tt][s] = dbl[row + s];
        Bsh[tt][s] = dbl[row + DTRv + s];
        Csh[tt][s] = dbl[row + DTRv + DSv + s];
    }
    __syncthreads();

    for (int tt = 0; tt < CL; tt++) {
        long token = (long)b*NN + t0 + tt;
        float dt = bdtv;
        #pragma unroll
        for (int k = 0; k < DTRv; k++) dt = fmaf(Dsh[tt][k], wdt[k], dt);
        float d   = softplusf(dt);
        float ucv = uc[token*DIv + di];
        float du  = d * ucv;
        float y = 0.f;
        #pragma unroll
        for (int s = 0; s < DSv; s++) {
            float a = expf(d * A[s]);
            h[s] = fmaf(a, h[s], du * Bsh[tt][s]);
            y = fmaf(h[s], Csh[tt][s], y);
        }
        float gq = ug[((long)token << 10) + DIv + di];
        uc[token*DIv + di] = fmaf(Dv, ucv, y) * siluf(gq);
    }
}

// ---------------------------------------------------------------------------
extern "C" void kernel_launch(void* const* d_in, const int* in_sizes, int n_in,
                              void* d_out, int out_size, void* d_ws, size_t ws_size,
                              hipStream_t stream)
{
    const float* xc     = (const float*)d_in[0];
    const float* yc     = (const float*)d_in[1];
    const float* xt     = (const float*)d_in[2];
    const float* yt     = (const float*)d_in[3];
    const float* We1    = (const float*)d_in[4];
    const float* be1    = (const float*)d_in[5];
    const float* We2    = (const float*)d_in[6];
    const float* be2    = (const float*)d_in[7];
    const float* norm_w = (const float*)d_in[8];
    const float* W_in   = (const float*)d_in[9];
    const float* W_conv = (const float*)d_in[10];
    const float* b_conv = (const float*)d_in[11];
    const float* W_xproj= (const float*)d_in[12];
    const float* W_dt   = (const float*)d_in[13];
    const float* b_dt   = (const float*)d_in[14];
    const float* A_log  = (const float*)d_in[15];
    const float* Dp     = (const float*)d_in[16];
    const float* W_out  = (const float*)d_in[17];

    float* z  = (float*)d_out;               // (B,N,DM) in place
    float* ws = (float*)d_ws;

    float* ug    = ws;                        // NTOK*1024 (also embed h1)
    float* uc    = ug    + (long)NTOK*2*DIv;  // NTOK*512  (becomes yg)
    float* dbl   = uc    + (long)NTOK*DIv;    // NTOK*64   [dt|B|C|0]
    float* rinv  = dbl   + (long)NTOK*64;     // NTOK
    float* Pbuf  = rinv  + NTOK;              // CCH*BB*DIv*DSv (also Hinit)
    float* hfin  = Pbuf  + (long)CCH*BB*DIv*DSv;
    float* Wxpad = hfin  + (long)CCH*BB*DIv*DSv;  // LL*512*64

    float* h1 = ug;  // alias: embed h1 lives in ug region until first gemm_in

    pad_wx_kernel<<<LL*DIv*64/256, 256, 0, stream>>>(W_xproj, Wxpad);

    embed_h1_kernel<<<NTOK, 256, 0, stream>>>(xc, yc, xt, yt, We1, be1, h1);
    gemm_k<32,128,32,4,4,false,false,true><<<dim3(DMv/128, NTOK/32), 256, 0, stream>>>(
        h1, We2, z, nullptr, nullptr, be2, NTOK, DMv, DMv);

    for (int l = 0; l < LL; l++) {
        rinv_kernel<<<NTOK/4, 256, 0, stream>>>(z, rinv);

        // ug = rmsnorm(z) @ W_in
        gemm_k<128,128,32,8,8,true,false,false><<<dim3(2*DIv/128, NTOK/128), 256, 0, stream>>>(
            z, W_in + (long)l*DMv*2*DIv, ug, rinv, norm_w + l*DMv, nullptr,
            NTOK, 2*DIv, DMv);

        conv_silu_kernel<<<NTOK*DIv/4/256, 256, 0, stream>>>(
            ug, W_conv + l*DIv*KK, b_conv + l*DIv, uc);

        // dbl = uc @ Wxpad[l]
        gemm_k<64,64,64,4,4,false,false,false><<<dim3(1, NTOK/64), 256, 0, stream>>>(
            uc, Wxpad + (long)l*DIv*64, dbl, nullptr, nullptr, nullptr,
            NTOK, 64, DIv);

        scanA_kernel<<<dim3(2, CCH, BB), 256, 0, stream>>>(
            dbl, uc, A_log + (long)l*DIv*DSv, W_dt + (long)l*DTRv*DIv,
            b_dt + l*DIv, Pbuf, hfin);

        scanB_kernel<<<BB*DIv*DSv/256, 256, 0, stream>>>(Pbuf, hfin);

        scanC_gate_kernel<<<dim3(2, CCH, BB), 256, 0, stream>>>(
            dbl, uc, A_log + (long)l*DIv*DSv, W_dt + (long)l*DTRv*DIv,
            b_dt + l*DIv, Pbuf, ug, Dp + l*DIv);

        // z += yg @ W_out   (yg lives in uc)
        gemm_k<32,128,32,4,4,false,true,false><<<dim3(DMv/128, NTOK/32), 256, 0, stream>>>(
            uc, W_out + (long)l*DIv*DMv, z, nullptr, nullptr, nullptr,
            NTOK, DMv, DIv);
    }
}

// Round 4
// 885.097 us; speedup vs baseline: 1.4232x; 1.1700x over previous
//
#include <hip/hip_runtime.h>
#include <hip/hip_bf16.h>

// Problem constants
#define BB 4
#define NCC 1792
#define NTT 256
#define NN 2048        // NCC + NTT
#define DMv 256
#define DIv 512
#define DSv 16
#define DTRv 16
#define KK 4
#define LL 4
#define NTOK (BB*NN)   // 8192

#define CCH 64         // chunks for scan
#define CL  32         // chunk length = NN/CCH

typedef short s16x8 __attribute__((ext_vector_type(8)));
typedef float f32x4 __attribute__((ext_vector_type(4)));

__device__ __forceinline__ float siluf(float x) {
    return x / (1.f + expf(-x));
}
__device__ __forceinline__ float softplusf(float x) {
    return fmaxf(x, 0.f) + log1pf(expf(-fabsf(x)));
}

// bf16 split helpers (round-to-nearest-even)
__device__ __forceinline__ ushort f2bf(float x) {
    uint u = __float_as_uint(x);
    u += 0x7fffu + ((u >> 16) & 1u);
    return (ushort)(u >> 16);
}
__device__ __forceinline__ float bf2f(ushort h) {
    return __uint_as_float(((uint)h) << 16);
}
__device__ __forceinline__ void split_bf(float x, ushort& hi, ushort& lo) {
    hi = f2bf(x);
    lo = f2bf(x - bf2f(hi));
}

// ---------------------------------------------------------------------------
// Weight prep: W [K][N] fp32 -> Wt_hi/Wt_lo [N][K] bf16
// ---------------------------------------------------------------------------
__global__ __launch_bounds__(256) void wprep_kernel(
    const float* __restrict__ W, ushort* __restrict__ th, ushort* __restrict__ tl,
    int K, int N)
{
    int idx = blockIdx.x*256 + threadIdx.x;   // over N*K
    int n = idx / K, k = idx - n*K;
    float v = W[(long)k*N + n];
    ushort hi, lo; split_bf(v, hi, lo);
    th[idx] = hi; tl[idx] = lo;
}

// ---------------------------------------------------------------------------
// Embed phase 1: h1 = relu(x*We1[0,:] + yprev*We1[1,:] + be1), split to bf16
// ---------------------------------------------------------------------------
__global__ __launch_bounds__(256) void embed_h1_kernel(
    const float* __restrict__ xc, const float* __restrict__ yc,
    const float* __restrict__ xt, const float* __restrict__ yt,
    const float* __restrict__ We1, const float* __restrict__ be1,
    ushort* __restrict__ h1h, ushort* __restrict__ h1l)
{
    int token = blockIdx.x;
    int b = token >> 11, t = token & (NN - 1);
    int d = threadIdx.x;

    float xv = (t < NCC) ? xc[b*NCC + t] : xt[b*NTT + (t - NCC)];
    float yp = 0.f;
    if (t > 0) {
        int tp = t - 1;
        yp = (tp < NCC) ? yc[b*NCC + tp] : yt[b*NTT + (tp - NCC)];
    }
    float h = fmaxf(fmaf(xv, We1[d], fmaf(yp, We1[DMv + d], be1[d])), 0.f);
    ushort hi, lo; split_bf(h, hi, lo);
    h1h[(long)token*DMv + d] = hi;
    h1l[(long)token*DMv + d] = lo;
}

// ---------------------------------------------------------------------------
// zn_prep: fused rmsnorm -> split bf16. 4 tokens per 256-thread block.
// ---------------------------------------------------------------------------
__global__ __launch_bounds__(256) void zn_prep_kernel(
    const float* __restrict__ z, const float* __restrict__ nw,
    ushort* __restrict__ znh, ushort* __restrict__ znl)
{
    int tid = threadIdx.x;
    int token = blockIdx.x*4 + (tid >> 6);
    int lane = tid & 63;
    float4 v = *(const float4*)&z[(long)token*DMv + lane*4];
    float ss = v.x*v.x + v.y*v.y + v.z*v.z + v.w*v.w;
    #pragma unroll
    for (int m = 32; m >= 1; m >>= 1) ss += __shfl_xor(ss, m, 64);
    float rinv = rsqrtf(ss * (1.f/DMv) + 1e-5f);
    float4 w = *(const float4*)&nw[lane*4];
    float a0 = v.x*rinv*w.x, a1 = v.y*rinv*w.y, a2 = v.z*rinv*w.z, a3 = v.w*rinv*w.w;
    ushort h0,l0,h1,l1,h2,l2,h3,l3;
    split_bf(a0,h0,l0); split_bf(a1,h1,l1); split_bf(a2,h2,l2); split_bf(a3,h3,l3);
    ushort4 hv = {h0,h1,h2,h3}, lv = {l0,l1,l2,l3};
    *(ushort4*)&znh[(long)token*DMv + lane*4] = hv;
    *(ushort4*)&znl[(long)token*DMv + lane*4] = lv;
}

// ---------------------------------------------------------------------------
// Split-bf16 MFMA GEMM: C[M,N] (+=C if RES, +bias if BIAS) = A @ B
// A given as hi/lo bf16 [M][lda-stride]; B as hi/lo bf16 [N][K] (transposed).
// BM=128 fixed, BN in {64,128}. 256 threads = 4 waves (2x2).
// acc += ah*bh + ah*bl + al*bh  (3 mfma per fragment pair)
// ---------------------------------------------------------------------------
template<int BN, bool RES, bool BIAS>
__global__ __launch_bounds__(256) void gemm_mfma(
    const ushort* __restrict__ Ah, const ushort* __restrict__ Al, int lda,
    const ushort* __restrict__ Bh, const ushort* __restrict__ Bl,
    float* __restrict__ C, const float* __restrict__ bias, int M, int N, int K)
{
    constexpr int BM = 128, BK = 32, PAD = 40;
    constexpr int NF  = BN / 32;              // n-frags per wave
    constexpr int AIT = BM*BK/8/256;          // ushort8 chunks per thread (A) = 2
    constexpr int BIT = BN*BK/8/256;          // (B) = 2 or 1

    __shared__ ushort As_h[BM*PAD], As_l[BM*PAD];
    __shared__ ushort Bs_h[BN*PAD], Bs_l[BN*PAD];

    int tid = threadIdx.x;
    int lane = tid & 63, wid = tid >> 6;
    int wm = wid >> 1, wn = wid & 1;
    int bm0 = blockIdx.y * BM, bn0 = blockIdx.x * BN;

    int fr = lane & 15;             // row/col within 16x16 fragment
    int fko = (lane >> 4) * 8;      // k offset of the 8-element run

    f32x4 acc[4][NF];
    #pragma unroll
    for (int i = 0; i < 4; i++)
        #pragma unroll
        for (int j = 0; j < NF; j++) acc[i][j] = (f32x4){0.f,0.f,0.f,0.f};

    s16x8 rAh[AIT], rAl[AIT], rBh[BIT], rBl[BIT];

    auto loadG = [&](int s) {
        #pragma unroll
        for (int i = 0; i < AIT; i++) {
            int id = tid + i*256; int r = id >> 2, c = (id & 3)*8;
            long g = (long)(bm0 + r)*lda + s*BK + c;
            rAh[i] = *(const s16x8*)(Ah + g);
            rAl[i] = *(const s16x8*)(Al + g);
        }
        #pragma unroll
        for (int i = 0; i < BIT; i++) {
            int id = tid + i*256; int r = id >> 2, c = (id & 3)*8;
            long g = (long)(bn0 + r)*K + s*BK + c;
            rBh[i] = *(const s16x8*)(Bh + g);
            rBl[i] = *(const s16x8*)(Bl + g);
        }
    };

    loadG(0);
    int nstep = K / BK;
    for (int s = 0;; s++) {
        // stage current regs to LDS
        #pragma unroll
        for (int i = 0; i < AIT; i++) {
            int id = tid + i*256; int r = id >> 2, c = (id & 3)*8;
            *(s16x8*)&As_h[r*PAD + c] = rAh[i];
            *(s16x8*)&As_l[r*PAD + c] = rAl[i];
        }
        #pragma unroll
        for (int i = 0; i < BIT; i++) {
            int id = tid + i*256; int r = id >> 2, c = (id & 3)*8;
            *(s16x8*)&Bs_h[r*PAD + c] = rBh[i];
            *(s16x8*)&Bs_l[r*PAD + c] = rBl[i];
        }
        __syncthreads();
        if (s + 1 < nstep) loadG(s + 1);   // prefetch overlaps MFMA

        s16x8 ah[4], al[4], bh[NF], bl[NF];
        #pragma unroll
        for (int f = 0; f < 4; f++) {
            int r = wm*64 + f*16 + fr;
            ah[f] = *(const s16x8*)&As_h[r*PAD + fko];
            al[f] = *(const s16x8*)&As_l[r*PAD + fko];
        }
        #pragma unroll
        for (int f = 0; f < NF; f++) {
            int r = wn*(BN/2) + f*16 + fr;
            bh[f] = *(const s16x8*)&Bs_h[r*PAD + fko];
            bl[f] = *(const s16x8*)&Bs_l[r*PAD + fko];
        }
        #pragma unroll
        for (int mf = 0; mf < 4; mf++)
            #pragma unroll
            for (int nf = 0; nf < NF; nf++) {
                acc[mf][nf] = __builtin_amdgcn_mfma_f32_16x16x32_bf16(ah[mf], bh[nf], acc[mf][nf], 0, 0, 0);
                acc[mf][nf] = __builtin_amdgcn_mfma_f32_16x16x32_bf16(ah[mf], bl[nf], acc[mf][nf], 0, 0, 0);
                acc[mf][nf] = __builtin_amdgcn_mfma_f32_16x16x32_bf16(al[mf], bh[nf], acc[mf][nf], 0, 0, 0);
            }
        if (s + 1 >= nstep) break;
        __syncthreads();
    }

    // epilogue: D layout col = lane&15, row = (lane>>4)*4 + j
    #pragma unroll
    for (int mf = 0; mf < 4; mf++) {
        #pragma unroll
        for (int nf = 0; nf < NF; nf++) {
            int row0 = bm0 + wm*64 + mf*16 + (lane >> 4)*4;
            int col  = bn0 + wn*(BN/2) + nf*16 + fr;
            float bv = BIAS ? bias[col] : 0.f;
            #pragma unroll
            for (int j = 0; j < 4; j++) {
                long off = (long)(row0 + j)*N + col;
                float v = acc[mf][nf][j] + bv;
                if (RES) v += C[off];
                C[off] = v;
            }
        }
    }
}

// ---------------------------------------------------------------------------
// Pad W_xproj (L,512,48) -> Wxpad (L,512,64), zero columns 48..63
// ---------------------------------------------------------------------------
__global__ __launch_bounds__(256) void pad_wx_kernel(
    const float* __restrict__ Wx, float* __restrict__ Wxpad)
{
    int idx = blockIdx.x*256 + threadIdx.x;       // L*512*64 total
    int o = idx & 63;
    int lk = idx >> 6;                            // l*512 + k
    Wxpad[idx] = (o < 48) ? Wx[lk*48 + o] : 0.f;
}

// ---------------------------------------------------------------------------
// fp32 GEMM (used only for the small 512->64 projection)
// ---------------------------------------------------------------------------
template<int BM, int BN, int BK, int TM, int TN, bool RES>
__global__ __launch_bounds__(256) void gemm_k(
    const float* __restrict__ A, const float* __restrict__ B,
    float* __restrict__ Cmat, int M, int N, int K)
{
    constexpr int TX = BN / TN;
    constexpr int TY = BM / TM;
    static_assert(TX * TY == 256, "bad cfg");

    __shared__ float As[BK][BM + 4];
    __shared__ float Bs[BK][BN + 4];

    int tid = threadIdx.x;
    int tx = tid % TX, ty = tid / TX;
    int bm0 = blockIdx.y * BM, bn0 = blockIdx.x * BN;

    float acc[TM][TN];
    #pragma unroll
    for (int i = 0; i < TM; i++)
        #pragma unroll
        for (int j = 0; j < TN; j++) acc[i][j] = 0.f;

    for (int k0 = 0; k0 < K; k0 += BK) {
        #pragma unroll
        for (int i = 0; i < BM*BK/(4*256); i++) {
            int idx4 = tid + i*256;
            int m  = idx4 / (BK/4);
            int k4 = idx4 % (BK/4);
            float4 v = *(const float4*)&A[(long)(bm0 + m)*K + k0 + k4*4];
            As[k4*4+0][m] = v.x; As[k4*4+1][m] = v.y;
            As[k4*4+2][m] = v.z; As[k4*4+3][m] = v.w;
        }
        #pragma unroll
        for (int i = 0; i < BK*BN/(4*256); i++) {
            int idx4 = tid + i*256;
            int k  = idx4 / (BN/4);
            int n4 = idx4 % (BN/4);
            *(float4*)&Bs[k][n4*4] = *(const float4*)&B[(long)(k0 + k)*N + bn0 + n4*4];
        }
        __syncthreads();

        #pragma unroll
        for (int k = 0; k < BK; k++) {
            float a[TM], bb[TN];
            #pragma unroll
            for (int i = 0; i < TM; i += 4) {
                float4 v = *(const float4*)&As[k][ty*TM + i];
                a[i] = v.x; a[i+1] = v.y; a[i+2] = v.z; a[i+3] = v.w;
            }
            #pragma unroll
            for (int j = 0; j < TN; j += 4) {
                float4 v = *(const float4*)&Bs[k][tx*TN + j];
                bb[j] = v.x; bb[j+1] = v.y; bb[j+2] = v.z; bb[j+3] = v.w;
            }
            #pragma unroll
            for (int i = 0; i < TM; i++)
                #pragma unroll
                for (int j = 0; j < TN; j++)
                    acc[i][j] = fmaf(a[i], bb[j], acc[i][j]);
        }
        __syncthreads();
    }

    #pragma unroll
    for (int i = 0; i < TM; i++) {
        #pragma unroll
        for (int j = 0; j < TN; j += 4) {
            long off = (long)(bm0 + ty*TM + i)*N + bn0 + tx*TN + j;
            float4 v;
            v.x = acc[i][j]; v.y = acc[i][j+1]; v.z = acc[i][j+2]; v.w = acc[i][j+3];
            if (RES) {
                float4 r = *(const float4*)&Cmat[off];
                v.x += r.x; v.y += r.y; v.z += r.z; v.w += r.w;
            }
            *(float4*)&Cmat[off] = v;
        }
    }
}

// ---------------------------------------------------------------------------
// Depthwise causal conv(K=4)+bias+SiLU, vectorized: thread = (token, 4 chans)
// ---------------------------------------------------------------------------
__global__ __launch_bounds__(256) void conv_silu_kernel(
    const float* __restrict__ ug, const float* __restrict__ Wc,
    const float* __restrict__ bcv, float* __restrict__ uc)
{
    int idx = blockIdx.x*256 + threadIdx.x;       // NTOK * DIv/4
    int di = (idx & (DIv/4 - 1)) * 4;
    int token = idx >> 7;
    int t = token & (NN - 1);

    float4 w0 = *(const float4*)&Wc[(di+0)*KK];
    float4 w1 = *(const float4*)&Wc[(di+1)*KK];
    float4 w2 = *(const float4*)&Wc[(di+2)*KK];
    float4 w3 = *(const float4*)&Wc[(di+3)*KK];
    float4 acc = *(const float4*)&bcv[di];

    float4 u;
    if (t >= 3) {
        u = *(const float4*)&ug[((long)(token-3) << 10) + di];
        acc.x = fmaf(u.x, w0.x, acc.x); acc.y = fmaf(u.y, w1.x, acc.y);
        acc.z = fmaf(u.z, w2.x, acc.z); acc.w = fmaf(u.w, w3.x, acc.w);
    }
    if (t >= 2) {
        u = *(const float4*)&ug[((long)(token-2) << 10) + di];
        acc.x = fmaf(u.x, w0.y, acc.x); acc.y = fmaf(u.y, w1.y, acc.y);
        acc.z = fmaf(u.z, w2.y, acc.z); acc.w = fmaf(u.w, w3.y, acc.w);
    }
    if (t >= 1) {
        u = *(const float4*)&ug[((long)(token-1) << 10) + di];
        acc.x = fmaf(u.x, w0.z, acc.x); acc.y = fmaf(u.y, w1.z, acc.y);
        acc.z = fmaf(u.z, w2.z, acc.z); acc.w = fmaf(u.w, w3.z, acc.w);
    }
    u = *(const float4*)&ug[((long)token << 10) + di];
    acc.x = fmaf(u.x, w0.w, acc.x); acc.y = fmaf(u.y, w1.w, acc.y);
    acc.z = fmaf(u.z, w2.w, acc.z); acc.w = fmaf(u.w, w3.w, acc.w);

    acc.x = siluf(acc.x); acc.y = siluf(acc.y);
    acc.z = siluf(acc.z); acc.w = siluf(acc.w);
    *(float4*)&uc[(long)token*DIv + di] = acc;
}

// ---------------------------------------------------------------------------
// Scan pass A: per-chunk local scan (h=0) -> decay product P, final h
// delta computed on the fly from dt (dbl cols 0..15) @ Wdt + bdt
// ---------------------------------------------------------------------------
__global__ __launch_bounds__(256) void scanA_kernel(
    const float* __restrict__ dbl, const float* __restrict__ uc,
    const float* __restrict__ Alog, const float* __restrict__ Wdt,
    const float* __restrict__ bdt,
    float* __restrict__ Pbuf, float* __restrict__ hfin)
{
    int half = blockIdx.x, c = blockIdx.y, b = blockIdx.z;
    int di = half*256 + threadIdx.x;

    float A[DSv], h[DSv], P[DSv], wdt[DTRv];
    #pragma unroll
    for (int s = 0; s < DSv; s++) {
        A[s] = -expf(Alog[di*DSv + s]);
        h[s] = 0.f; P[s] = 1.f;
    }
    #pragma unroll
    for (int k = 0; k < DTRv; k++) wdt[k] = Wdt[k*DIv + di];
    float bdtv = bdt[di];

    __shared__ float Dsh[CL][DTRv];
    __shared__ float Bsh[CL][DSv];
    int t0 = c * CL;
    for (int i = threadIdx.x; i < CL*DSv; i += 256) {
        int tt = i >> 4, s = i & 15;
        long row = (long)(b*NN + t0 + tt) * 64;
        Dsh[tt][s] = dbl[row + s];
        Bsh[tt][s] = dbl[row + DTRv + s];
    }
    __syncthreads();

    for (int tt = 0; tt < CL; tt++) {
        long token = (long)b*NN + t0 + tt;
        float dt = bdtv;
        #pragma unroll
        for (int k = 0; k < DTRv; k++) dt = fmaf(Dsh[tt][k], wdt[k], dt);
        float d  = softplusf(dt);
        float du = d * uc[token*DIv + di];
        #pragma unroll
        for (int s = 0; s < DSv; s++) {
            float a = expf(d * A[s]);
            P[s] *= a;
            h[s] = fmaf(a, h[s], du * Bsh[tt][s]);
        }
    }
    long base = (((long)c*BB + b)*DIv + di)*DSv;
    #pragma unroll
    for (int s = 0; s < DSv; s++) { Pbuf[base+s] = P[s]; hfin[base+s] = h[s]; }
}

// ---------------------------------------------------------------------------
// Scan pass B: sequential over chunks; Pbuf overwritten with chunk-initial H
// ---------------------------------------------------------------------------
__global__ __launch_bounds__(256) void scanB_kernel(
    float* __restrict__ Pbuf, const float* __restrict__ hfin)
{
    int id = blockIdx.x * 256 + threadIdx.x;  // (b*512+di)*16+s
    float H = 0.f;
    for (int c = 0; c < CCH; c++) {
        long idx = (long)c * (BB*DIv*DSv) + id;
        float p  = Pbuf[idx];
        float hf = hfin[idx];
        Pbuf[idx] = H;               // becomes Hinit
        H = fmaf(p, H, hf);
    }
}

// ---------------------------------------------------------------------------
// Scan pass C + gate: yg = (y + D*u)*silu(gate), written as split-bf16
// into the (dead) u-half of ug rows: [512 hi | 512 lo] ushorts per token.
// ---------------------------------------------------------------------------
__global__ __launch_bounds__(256) void scanC_gate_kernel(
    const float* __restrict__ dbl, const float* __restrict__ uc,
    const float* __restrict__ Alog, const float* __restrict__ Wdt,
    const float* __restrict__ bdt, const float* __restrict__ Hinit,
    float* __restrict__ ug, const float* __restrict__ Dp)
{
    int half = blockIdx.x, c = blockIdx.y, b = blockIdx.z;
    int di = half*256 + threadIdx.x;

    float A[DSv], h[DSv], wdt[DTRv];
    long base = (((long)c*BB + b)*DIv + di)*DSv;
    #pragma unroll
    for (int s = 0; s < DSv; s++) {
        A[s] = -expf(Alog[di*DSv + s]);
        h[s] = Hinit[base + s];
    }
    #pragma unroll
    for (int k = 0; k < DTRv; k++) wdt[k] = Wdt[k*DIv + di];
    float bdtv = bdt[di];
    float Dv = Dp[di];

    __shared__ float Dsh[CL][DTRv];
    __shared__ float Bsh[CL][DSv];
    __shared__ float Csh[CL][DSv];
    int t0 = c * CL;
    for (int i = threadIdx.x; i < CL*DSv; i += 256) {
        int tt = i >> 4, s = i & 15;
        long row = (long)(b*NN + t0 + tt) * 64;
        Dsh[tt][s] = dbl[row + s];
        Bsh[tt][s] = dbl[row + DTRv + s];
        Csh[tt][s] = dbl[row + DTRv + DSv + s];
    }
    __syncthreads();

    for (int tt = 0; tt < CL; tt++) {
        long token = (long)b*NN + t0 + tt;
        float dt = bdtv;
        #pragma unroll
        for (int k = 0; k < DTRv; k++) dt = fmaf(Dsh[tt][k], wdt[k], dt);
        float d   = softplusf(dt);
        float ucv = uc[token*DIv + di];
        float du  = d * ucv;
        float y = 0.f;
        #pragma unroll
        for (int s = 0; s < DSv; s++) {
            float a = expf(d * A[s]);
            h[s] = fmaf(a, h[s], du * Bsh[tt][s]);
            y = fmaf(h[s], Csh[tt][s], y);
        }
        float gq = ug[((long)token << 10) + DIv + di];
        float ygv = fmaf(Dv, ucv, y) * siluf(gq);
        ushort hi, lo; split_bf(ygv, hi, lo);
        ushort* ygrow = (ushort*)(ug + ((long)token << 10));
        ygrow[di] = hi;
        ygrow[DIv + di] = lo;
    }
}

// ---------------------------------------------------------------------------
extern "C" void kernel_launch(void* const* d_in, const int* in_sizes, int n_in,
                              void* d_out, int out_size, void* d_ws, size_t ws_size,
                              hipStream_t stream)
{
    const float* xc     = (const float*)d_in[0];
    const float* yc     = (const float*)d_in[1];
    const float* xt     = (const float*)d_in[2];
    const float* yt     = (const float*)d_in[3];
    const float* We1    = (const float*)d_in[4];
    const float* be1    = (const float*)d_in[5];
    const float* We2    = (const float*)d_in[6];
    const float* be2    = (const float*)d_in[7];
    const float* norm_w = (const float*)d_in[8];
    const float* W_in   = (const float*)d_in[9];
    const float* W_conv = (const float*)d_in[10];
    const float* b_conv = (const float*)d_in[11];
    const float* W_xproj= (const float*)d_in[12];
    const float* W_dt   = (const float*)d_in[13];
    const float* b_dt   = (const float*)d_in[14];
    const float* A_log  = (const float*)d_in[15];
    const float* Dp     = (const float*)d_in[16];
    const float* W_out  = (const float*)d_in[17];

    float* z  = (float*)d_out;               // (B,N,DM) in place
    float* ws = (float*)d_ws;

    float* ug    = ws;                        // NTOK*1024 f32 (u|gate; u-half becomes yg bf16)
    float* uc    = ug    + (long)NTOK*2*DIv;  // NTOK*512 f32
    float* dbl   = uc    + (long)NTOK*DIv;    // NTOK*64 f32 [dt|B|C|0]
    float* Pbuf  = dbl   + (long)NTOK*64;     // CCH*BB*DIv*DSv (becomes Hinit)
    float* hfin  = Pbuf  + (long)CCH*BB*DIv*DSv;
    float* Wxpad = hfin  + (long)CCH*BB*DIv*DSv;  // LL*512*64

    ushort* znh = (ushort*)(Wxpad + (long)LL*DIv*64);  // NTOK*256
    ushort* znl = znh + (long)NTOK*DMv;
    ushort* We2h = znl + (long)NTOK*DMv;               // 256*256
    ushort* We2l = We2h + DMv*DMv;
    ushort* Winh = We2l + DMv*DMv;                     // LL * 1024*256
    ushort* Winl = Winh + (long)LL*2*DIv*DMv;
    ushort* Wouth = Winl + (long)LL*2*DIv*DMv;         // LL * 256*512
    ushort* Woutl = Wouth + (long)LL*DMv*DIv;

    // --- one-time weight prep ---
    wprep_kernel<<<DMv*DMv/256, 256, 0, stream>>>(We2, We2h, We2l, DMv, DMv);
    for (int l = 0; l < LL; l++) {
        wprep_kernel<<<DMv*2*DIv/256, 256, 0, stream>>>(
            W_in + (long)l*DMv*2*DIv, Winh + (long)l*2*DIv*DMv, Winl + (long)l*2*DIv*DMv,
            DMv, 2*DIv);
        wprep_kernel<<<DIv*DMv/256, 256, 0, stream>>>(
            W_out + (long)l*DIv*DMv, Wouth + (long)l*DMv*DIv, Woutl + (long)l*DMv*DIv,
            DIv, DMv);
    }
    pad_wx_kernel<<<LL*DIv*64/256, 256, 0, stream>>>(W_xproj, Wxpad);

    // --- embed ---
    embed_h1_kernel<<<NTOK, 256, 0, stream>>>(xc, yc, xt, yt, We1, be1, znh, znl);
    gemm_mfma<64,false,true><<<dim3(DMv/64, NTOK/128), 256, 0, stream>>>(
        znh, znl, DMv, We2h, We2l, z, be2, NTOK, DMv, DMv);

    for (int l = 0; l < LL; l++) {
        zn_prep_kernel<<<NTOK/4, 256, 0, stream>>>(z, norm_w + l*DMv, znh, znl);

        // ug = rmsnorm(z) @ W_in
        gemm_mfma<128,false,false><<<dim3(2*DIv/128, NTOK/128), 256, 0, stream>>>(
            znh, znl, DMv, Winh + (long)l*2*DIv*DMv, Winl + (long)l*2*DIv*DMv,
            ug, nullptr, NTOK, 2*DIv, DMv);

        conv_silu_kernel<<<NTOK*DIv/4/256, 256, 0, stream>>>(
            ug, W_conv + l*DIv*KK, b_conv + l*DIv, uc);

        // dbl = uc @ Wxpad[l]   (small fp32 GEMM)
        gemm_k<64,64,64,4,4,false><<<dim3(1, NTOK/64), 256, 0, stream>>>(
            uc, Wxpad + (long)l*DIv*64, dbl, NTOK, 64, DIv);

        scanA_kernel<<<dim3(2, CCH, BB), 256, 0, stream>>>(
            dbl, uc, A_log + (long)l*DIv*DSv, W_dt + (long)l*DTRv*DIv,
            b_dt + l*DIv, Pbuf, hfin);

        scanB_kernel<<<BB*DIv*DSv/256, 256, 0, stream>>>(Pbuf, hfin);

        scanC_gate_kernel<<<dim3(2, CCH, BB), 256, 0, stream>>>(
            dbl, uc, A_log + (long)l*DIv*DSv, W_dt + (long)l*DTRv*DIv,
            b_dt + l*DIv, Pbuf, ug, Dp + l*DIv);

        // z += yg @ W_out   (yg = split-bf16 in ug rows, stride 2048 ushorts)
        gemm_mfma<64,true,false><<<dim3(DMv/64, NTOK/128), 256, 0, stream>>>(
            (ushort*)ug, (ushort*)ug + DIv, 4*DIv,
            Wouth + (long)l*DMv*DIv, Woutl + (long)l*DMv*DIv,
            z, nullptr, NTOK, DMv, DIv);
    }
}

// Round 5
// 706.619 us; speedup vs baseline: 1.7827x; 1.2526x over previous
//
#include <hip/hip_runtime.h>
#include <hip/hip_bf16.h>

// Problem constants
#define BB 4
#define NCC 1792
#define NTT 256
#define NN 2048        // NCC + NTT
#define DMv 256
#define DIv 512
#define DSv 16
#define DTRv 16
#define KK 4
#define LL 4
#define NTOK (BB*NN)   // 8192

#define CCH 64         // chunks for scan
#define CL  32         // chunk length = NN/CCH

#define LOG2E 1.44269504088896f

typedef short s16x8 __attribute__((ext_vector_type(8)));
typedef float f32x4 __attribute__((ext_vector_type(4)));

__device__ __forceinline__ float fast_rcp(float x) {
    return __builtin_amdgcn_rcpf(x);
}
__device__ __forceinline__ float silu_fast(float x) {
    return x * fast_rcp(1.f + __expf(-x));
}
__device__ __forceinline__ float softplus_fast(float x) {
    return fmaxf(x, 0.f) + __logf(1.f + __expf(-fabsf(x)));
}

// bf16 split helpers (round-to-nearest-even)
__device__ __forceinline__ ushort f2bf(float x) {
    uint u = __float_as_uint(x);
    u += 0x7fffu + ((u >> 16) & 1u);
    return (ushort)(u >> 16);
}
__device__ __forceinline__ float bf2f(ushort h) {
    return __uint_as_float(((uint)h) << 16);
}
__device__ __forceinline__ void split_bf(float x, ushort& hi, ushort& lo) {
    hi = f2bf(x);
    lo = f2bf(x - bf2f(hi));
}

// ---------------------------------------------------------------------------
// Weight prep: W [nl][K][N] fp32 -> th/tl [nl][N][K] bf16 (hi/lo)
// launched with grid = nl*N*K/256
// ---------------------------------------------------------------------------
__global__ __launch_bounds__(256) void wprep_kernel(
    const float* __restrict__ W, ushort* __restrict__ th, ushort* __restrict__ tl,
    int K, int N)
{
    int idx = blockIdx.x*256 + threadIdx.x;
    int perL = N*K;
    int l = idx / perL, r = idx - l*perL;
    int n = r / K, k = r - n*K;
    float v = W[(long)l*perL + (long)k*N + n];
    ushort hi, lo; split_bf(v, hi, lo);
    th[idx] = hi; tl[idx] = lo;
}

// ---------------------------------------------------------------------------
// Wx prep: W_xproj (L,512,48) -> WxT (L,64,512) bf16 hi/lo, rows 48..63 zero
// ---------------------------------------------------------------------------
__global__ __launch_bounds__(256) void wxprep_kernel(
    const float* __restrict__ Wx, ushort* __restrict__ th, ushort* __restrict__ tl)
{
    int idx = blockIdx.x*256 + threadIdx.x;   // L*64*512
    int l = idx >> 15;
    int r = idx & 32767;
    int o = r >> 9, k = r & 511;
    float v = (o < 48) ? Wx[((long)l*DIv + k)*48 + o] : 0.f;
    ushort hi, lo; split_bf(v, hi, lo);
    th[idx] = hi; tl[idx] = lo;
}

// ---------------------------------------------------------------------------
// Embed phase 1: h1 = relu(x*We1[0,:] + yprev*We1[1,:] + be1), split to bf16
// ---------------------------------------------------------------------------
__global__ __launch_bounds__(256) void embed_h1_kernel(
    const float* __restrict__ xc, const float* __restrict__ yc,
    const float* __restrict__ xt, const float* __restrict__ yt,
    const float* __restrict__ We1, const float* __restrict__ be1,
    ushort* __restrict__ h1h, ushort* __restrict__ h1l)
{
    int token = blockIdx.x;
    int b = token >> 11, t = token & (NN - 1);
    int d = threadIdx.x;

    float xv = (t < NCC) ? xc[b*NCC + t] : xt[b*NTT + (t - NCC)];
    float yp = 0.f;
    if (t > 0) {
        int tp = t - 1;
        yp = (tp < NCC) ? yc[b*NCC + tp] : yt[b*NTT + (tp - NCC)];
    }
    float h = fmaxf(fmaf(xv, We1[d], fmaf(yp, We1[DMv + d], be1[d])), 0.f);
    ushort hi, lo; split_bf(h, hi, lo);
    h1h[(long)token*DMv + d] = hi;
    h1l[(long)token*DMv + d] = lo;
}

// ---------------------------------------------------------------------------
// zn_prep: fused rmsnorm -> split bf16. 4 tokens per 256-thread block.
// ---------------------------------------------------------------------------
__global__ __launch_bounds__(256) void zn_prep_kernel(
    const float* __restrict__ z, const float* __restrict__ nw,
    ushort* __restrict__ znh, ushort* __restrict__ znl)
{
    int tid = threadIdx.x;
    int token = blockIdx.x*4 + (tid >> 6);
    int lane = tid & 63;
    float4 v = *(const float4*)&z[(long)token*DMv + lane*4];
    float ss = v.x*v.x + v.y*v.y + v.z*v.z + v.w*v.w;
    #pragma unroll
    for (int m = 32; m >= 1; m >>= 1) ss += __shfl_xor(ss, m, 64);
    float rinv = rsqrtf(ss * (1.f/DMv) + 1e-5f);
    float4 w = *(const float4*)&nw[lane*4];
    float a0 = v.x*rinv*w.x, a1 = v.y*rinv*w.y, a2 = v.z*rinv*w.z, a3 = v.w*rinv*w.w;
    ushort h0,l0,h1,l1,h2,l2,h3,l3;
    split_bf(a0,h0,l0); split_bf(a1,h1,l1); split_bf(a2,h2,l2); split_bf(a3,h3,l3);
    ushort4 hv = {h0,h1,h2,h3}, lv = {l0,l1,l2,l3};
    *(ushort4*)&znh[(long)token*DMv + lane*4] = hv;
    *(ushort4*)&znl[(long)token*DMv + lane*4] = lv;
}

// ---------------------------------------------------------------------------
// Split-bf16 MFMA GEMM: C[M,N] (+=C if RES, +bias if BIAS) = A @ B^T
// A hi/lo bf16 [M][lda]; B hi/lo bf16 [N][K]. 256 threads = 4 waves (WMxWN).
// acc += ah*bh + ah*bl + al*bh
// ---------------------------------------------------------------------------
template<int BM, int BN, int WM, int WN, bool RES, bool BIAS>
__global__ __launch_bounds__(256) void gemm_mfma(
    const ushort* __restrict__ Ah, const ushort* __restrict__ Al, int lda,
    const ushort* __restrict__ Bh, const ushort* __restrict__ Bl,
    float* __restrict__ C, const float* __restrict__ bias, int M, int N, int K)
{
    constexpr int BK = 32, PAD = 40;
    constexpr int MF = BM/WM/16, NF = BN/WN/16;
    constexpr int AIT = BM*BK/8/256;
    constexpr int BIT = BN*BK/8/256;
    static_assert(WM*WN == 4, "4 waves");

    __shared__ ushort As_h[BM*PAD], As_l[BM*PAD];
    __shared__ ushort Bs_h[BN*PAD], Bs_l[BN*PAD];

    int tid = threadIdx.x;
    int lane = tid & 63, wid = tid >> 6;
    int wm = wid / WN, wn = wid % WN;
    int bm0 = blockIdx.y * BM, bn0 = blockIdx.x * BN;

    int fr = lane & 15;
    int fko = (lane >> 4) * 8;

    f32x4 acc[MF][NF];
    #pragma unroll
    for (int i = 0; i < MF; i++)
        #pragma unroll
        for (int j = 0; j < NF; j++) acc[i][j] = (f32x4){0.f,0.f,0.f,0.f};

    s16x8 rAh[AIT], rAl[AIT], rBh[BIT], rBl[BIT];

    auto loadG = [&](int s) {
        #pragma unroll
        for (int i = 0; i < AIT; i++) {
            int id = tid + i*256; int r = id >> 2, c = (id & 3)*8;
            long g = (long)(bm0 + r)*lda + s*BK + c;
            rAh[i] = *(const s16x8*)(Ah + g);
            rAl[i] = *(const s16x8*)(Al + g);
        }
        #pragma unroll
        for (int i = 0; i < BIT; i++) {
            int id = tid + i*256; int r = id >> 2, c = (id & 3)*8;
            long g = (long)(bn0 + r)*K + s*BK + c;
            rBh[i] = *(const s16x8*)(Bh + g);
            rBl[i] = *(const s16x8*)(Bl + g);
        }
    };

    loadG(0);
    int nstep = K / BK;
    for (int s = 0;; s++) {
        #pragma unroll
        for (int i = 0; i < AIT; i++) {
            int id = tid + i*256; int r = id >> 2, c = (id & 3)*8;
            *(s16x8*)&As_h[r*PAD + c] = rAh[i];
            *(s16x8*)&As_l[r*PAD + c] = rAl[i];
        }
        #pragma unroll
        for (int i = 0; i < BIT; i++) {
            int id = tid + i*256; int r = id >> 2, c = (id & 3)*8;
            *(s16x8*)&Bs_h[r*PAD + c] = rBh[i];
            *(s16x8*)&Bs_l[r*PAD + c] = rBl[i];
        }
        __syncthreads();
        if (s + 1 < nstep) loadG(s + 1);

        s16x8 ah[MF], al[MF], bh[NF], bl[NF];
        #pragma unroll
        for (int f = 0; f < MF; f++) {
            int r = (wm*MF + f)*16 + fr;
            ah[f] = *(const s16x8*)&As_h[r*PAD + fko];
            al[f] = *(const s16x8*)&As_l[r*PAD + fko];
        }
        #pragma unroll
        for (int f = 0; f < NF; f++) {
            int r = (wn*NF + f)*16 + fr;
            bh[f] = *(const s16x8*)&Bs_h[r*PAD + fko];
            bl[f] = *(const s16x8*)&Bs_l[r*PAD + fko];
        }
        #pragma unroll
        for (int mf = 0; mf < MF; mf++)
            #pragma unroll
            for (int nf = 0; nf < NF; nf++) {
                acc[mf][nf] = __builtin_amdgcn_mfma_f32_16x16x32_bf16(ah[mf], bh[nf], acc[mf][nf], 0, 0, 0);
                acc[mf][nf] = __builtin_amdgcn_mfma_f32_16x16x32_bf16(ah[mf], bl[nf], acc[mf][nf], 0, 0, 0);
                acc[mf][nf] = __builtin_amdgcn_mfma_f32_16x16x32_bf16(al[mf], bh[nf], acc[mf][nf], 0, 0, 0);
            }
        if (s + 1 >= nstep) break;
        __syncthreads();
    }

    #pragma unroll
    for (int mf = 0; mf < MF; mf++) {
        #pragma unroll
        for (int nf = 0; nf < NF; nf++) {
            int row0 = bm0 + (wm*MF + mf)*16 + (lane >> 4)*4;
            int col  = bn0 + (wn*NF + nf)*16 + fr;
            float bv = BIAS ? bias[col] : 0.f;
            #pragma unroll
            for (int j = 0; j < 4; j++) {
                long off = (long)(row0 + j)*N + col;
                float v = acc[mf][nf][j] + bv;
                if (RES) v += C[off];
                C[off] = v;
            }
        }
    }
}

// ---------------------------------------------------------------------------
// Depthwise causal conv(K=4)+bias+SiLU: f32 out + split-bf16 out
// ---------------------------------------------------------------------------
__global__ __launch_bounds__(256) void conv_silu_kernel(
    const float* __restrict__ ug, const float* __restrict__ Wc,
    const float* __restrict__ bcv, float* __restrict__ uc,
    ushort* __restrict__ uch, ushort* __restrict__ ucl)
{
    int idx = blockIdx.x*256 + threadIdx.x;       // NTOK * DIv/4
    int di = (idx & (DIv/4 - 1)) * 4;
    int token = idx >> 7;
    int t = token & (NN - 1);

    float4 w0 = *(const float4*)&Wc[(di+0)*KK];
    float4 w1 = *(const float4*)&Wc[(di+1)*KK];
    float4 w2 = *(const float4*)&Wc[(di+2)*KK];
    float4 w3 = *(const float4*)&Wc[(di+3)*KK];
    float4 acc = *(const float4*)&bcv[di];

    float4 u;
    if (t >= 3) {
        u = *(const float4*)&ug[((long)(token-3) << 10) + di];
        acc.x = fmaf(u.x, w0.x, acc.x); acc.y = fmaf(u.y, w1.x, acc.y);
        acc.z = fmaf(u.z, w2.x, acc.z); acc.w = fmaf(u.w, w3.x, acc.w);
    }
    if (t >= 2) {
        u = *(const float4*)&ug[((long)(token-2) << 10) + di];
        acc.x = fmaf(u.x, w0.y, acc.x); acc.y = fmaf(u.y, w1.y, acc.y);
        acc.z = fmaf(u.z, w2.y, acc.z); acc.w = fmaf(u.w, w3.y, acc.w);
    }
    if (t >= 1) {
        u = *(const float4*)&ug[((long)(token-1) << 10) + di];
        acc.x = fmaf(u.x, w0.z, acc.x); acc.y = fmaf(u.y, w1.z, acc.y);
        acc.z = fmaf(u.z, w2.z, acc.z); acc.w = fmaf(u.w, w3.z, acc.w);
    }
    u = *(const float4*)&ug[((long)token << 10) + di];
    acc.x = fmaf(u.x, w0.w, acc.x); acc.y = fmaf(u.y, w1.w, acc.y);
    acc.z = fmaf(u.z, w2.w, acc.z); acc.w = fmaf(u.w, w3.w, acc.w);

    acc.x = silu_fast(acc.x); acc.y = silu_fast(acc.y);
    acc.z = silu_fast(acc.z); acc.w = silu_fast(acc.w);
    *(float4*)&uc[(long)token*DIv + di] = acc;

    ushort h0,l0,h1,l1,h2,l2,h3,l3;
    split_bf(acc.x,h0,l0); split_bf(acc.y,h1,l1);
    split_bf(acc.z,h2,l2); split_bf(acc.w,h3,l3);
    ushort4 hv = {h0,h1,h2,h3}, lv = {l0,l1,l2,l3};
    *(ushort4*)&uch[(long)token*DIv + di] = hv;
    *(ushort4*)&ucl[(long)token*DIv + di] = lv;
}

// ---------------------------------------------------------------------------
// Scan pass A: per-chunk local scan (h=0) -> decay product P, final h
// dblT layout: [64 rows][NTOK]; rows 0..15 dt, 16..31 B, 32..47 C
// ---------------------------------------------------------------------------
__global__ __launch_bounds__(256) void scanA_kernel(
    const float* __restrict__ dblT, const float* __restrict__ uc,
    const float* __restrict__ Alog, const float* __restrict__ Wdt,
    const float* __restrict__ bdt,
    float* __restrict__ Pbuf, float* __restrict__ hfin)
{
    int half = blockIdx.x, c = blockIdx.y, b = blockIdx.z;
    int di = half*256 + threadIdx.x;

    float A2[DSv], h[DSv], P[DSv], wdt[DTRv];
    #pragma unroll
    for (int s = 0; s < DSv; s++) {
        A2[s] = -expf(Alog[di*DSv + s]) * LOG2E;
        h[s] = 0.f; P[s] = 1.f;
    }
    #pragma unroll
    for (int k = 0; k < DTRv; k++) wdt[k] = Wdt[k*DIv + di];
    float bdtv = bdt[di];

    __shared__ float Dsh[CL][DSv+1];
    __shared__ float Bsh[CL][DSv+1];
    int t0 = c * CL;
    #pragma unroll
    for (int i = threadIdx.x; i < CL*DSv; i += 256) {
        int s = i >> 5, tt = i & 31;
        long gb = (long)b*NN + t0 + tt;
        Dsh[tt][s] = dblT[(long)s*NTOK + gb];
        Bsh[tt][s] = dblT[(long)(DTRv + s)*NTOK + gb];
    }
    __syncthreads();

    for (int tt = 0; tt < CL; tt++) {
        long token = (long)b*NN + t0 + tt;
        float dt = bdtv;
        #pragma unroll
        for (int k = 0; k < DTRv; k++) dt = fmaf(Dsh[tt][k], wdt[k], dt);
        float d  = softplus_fast(dt);
        float du = d * uc[token*DIv + di];
        #pragma unroll
        for (int s = 0; s < DSv; s++) {
            float a = exp2f(d * A2[s]);
            P[s] *= a;
            h[s] = fmaf(a, h[s], du * Bsh[tt][s]);
        }
    }
    long base = (((long)c*BB + b)*DIv + di)*DSv;
    #pragma unroll
    for (int s = 0; s < DSv; s++) { Pbuf[base+s] = P[s]; hfin[base+s] = h[s]; }
}

// ---------------------------------------------------------------------------
// Scan pass B: sequential over chunks; Pbuf overwritten with chunk-initial H
// ---------------------------------------------------------------------------
__global__ __launch_bounds__(256) void scanB_kernel(
    float* __restrict__ Pbuf, const float* __restrict__ hfin)
{
    int id = blockIdx.x * 256 + threadIdx.x;  // (b*512+di)*16+s
    float H = 0.f;
    for (int c = 0; c < CCH; c++) {
        long idx = (long)c * (BB*DIv*DSv) + id;
        float p  = Pbuf[idx];
        float hf = hfin[idx];
        Pbuf[idx] = H;               // becomes Hinit
        H = fmaf(p, H, hf);
    }
}

// ---------------------------------------------------------------------------
// Scan pass C + gate: yg = (y + D*u)*silu(gate), written as split-bf16
// into the (dead) u-half of ug rows: [512 hi | 512 lo] ushorts per token.
// ---------------------------------------------------------------------------
__global__ __launch_bounds__(256) void scanC_gate_kernel(
    const float* __restrict__ dblT, const float* __restrict__ uc,
    const float* __restrict__ Alog, const float* __restrict__ Wdt,
    const float* __restrict__ bdt, const float* __restrict__ Hinit,
    float* __restrict__ ug, const float* __restrict__ Dp)
{
    int half = blockIdx.x, c = blockIdx.y, b = blockIdx.z;
    int di = half*256 + threadIdx.x;

    float A2[DSv], h[DSv], wdt[DTRv];
    long base = (((long)c*BB + b)*DIv + di)*DSv;
    #pragma unroll
    for (int s = 0; s < DSv; s++) {
        A2[s] = -expf(Alog[di*DSv + s]) * LOG2E;
        h[s] = Hinit[base + s];
    }
    #pragma unroll
    for (int k = 0; k < DTRv; k++) wdt[k] = Wdt[k*DIv + di];
    float bdtv = bdt[di];
    float Dv = Dp[di];

    __shared__ float Dsh[CL][DSv+1];
    __shared__ float Bsh[CL][DSv+1];
    __shared__ float Csh[CL][DSv+1];
    int t0 = c * CL;
    #pragma unroll
    for (int i = threadIdx.x; i < CL*DSv; i += 256) {
        int s = i >> 5, tt = i & 31;
        long gb = (long)b*NN + t0 + tt;
        Dsh[tt][s] = dblT[(long)s*NTOK + gb];
        Bsh[tt][s] = dblT[(long)(DTRv + s)*NTOK + gb];
        Csh[tt][s] = dblT[(long)(DTRv + DSv + s)*NTOK + gb];
    }
    __syncthreads();

    for (int tt = 0; tt < CL; tt++) {
        long token = (long)b*NN + t0 + tt;
        float dt = bdtv;
        #pragma unroll
        for (int k = 0; k < DTRv; k++) dt = fmaf(Dsh[tt][k], wdt[k], dt);
        float d   = softplus_fast(dt);
        float ucv = uc[token*DIv + di];
        float du  = d * ucv;
        float y = 0.f;
        #pragma unroll
        for (int s = 0; s < DSv; s++) {
            float a = exp2f(d * A2[s]);
            h[s] = fmaf(a, h[s], du * Bsh[tt][s]);
            y = fmaf(h[s], Csh[tt][s], y);
        }
        float gq = ug[((long)token << 10) + DIv + di];
        float ygv = fmaf(Dv, ucv, y) * silu_fast(gq);
        ushort hi, lo; split_bf(ygv, hi, lo);
        ushort* ygrow = (ushort*)(ug + ((long)token << 10));
        ygrow[di] = hi;
        ygrow[DIv + di] = lo;
    }
}

// ---------------------------------------------------------------------------
extern "C" void kernel_launch(void* const* d_in, const int* in_sizes, int n_in,
                              void* d_out, int out_size, void* d_ws, size_t ws_size,
                              hipStream_t stream)
{
    const float* xc     = (const float*)d_in[0];
    const float* yc     = (const float*)d_in[1];
    const float* xt     = (const float*)d_in[2];
    const float* yt     = (const float*)d_in[3];
    const float* We1    = (const float*)d_in[4];
    const float* be1    = (const float*)d_in[5];
    const float* We2    = (const float*)d_in[6];
    const float* be2    = (const float*)d_in[7];
    const float* norm_w = (const float*)d_in[8];
    const float* W_in   = (const float*)d_in[9];
    const float* W_conv = (const float*)d_in[10];
    const float* b_conv = (const float*)d_in[11];
    const float* W_xproj= (const float*)d_in[12];
    const float* W_dt   = (const float*)d_in[13];
    const float* b_dt   = (const float*)d_in[14];
    const float* A_log  = (const float*)d_in[15];
    const float* Dp     = (const float*)d_in[16];
    const float* W_out  = (const float*)d_in[17];

    float* z  = (float*)d_out;               // (B,N,DM) in place
    float* ws = (float*)d_ws;

    float* ug    = ws;                        // NTOK*1024 f32 (u|gate; u-half becomes yg bf16)
    float* uc    = ug    + (long)NTOK*2*DIv;  // NTOK*512 f32
    float* dblT  = uc    + (long)NTOK*DIv;    // 64*NTOK f32 [dt|B|C|0] transposed
    float* Pbuf  = dblT  + (long)64*NTOK;     // CCH*BB*DIv*DSv (becomes Hinit)
    float* hfin  = Pbuf  + (long)CCH*BB*DIv*DSv;

    ushort* uch  = (ushort*)(hfin + (long)CCH*BB*DIv*DSv); // NTOK*512
    ushort* ucl  = uch + (long)NTOK*DIv;
    ushort* znh  = ucl + (long)NTOK*DIv;                   // NTOK*256
    ushort* znl  = znh + (long)NTOK*DMv;
    ushort* We2h = znl + (long)NTOK*DMv;                   // 256*256
    ushort* We2l = We2h + DMv*DMv;
    ushort* Winh = We2l + DMv*DMv;                         // LL*1024*256
    ushort* Winl = Winh + (long)LL*2*DIv*DMv;
    ushort* Wouth= Winl + (long)LL*2*DIv*DMv;              // LL*256*512
    ushort* Woutl= Wouth + (long)LL*DMv*DIv;
    ushort* WxTh = Woutl + (long)LL*DMv*DIv;               // LL*64*512
    ushort* WxTl = WxTh + (long)LL*64*DIv;

    // --- one-time weight prep (batched over layers) ---
    wprep_kernel<<<DMv*DMv/256, 256, 0, stream>>>(We2, We2h, We2l, DMv, DMv);
    wprep_kernel<<<LL*DMv*2*DIv/256, 256, 0, stream>>>(W_in, Winh, Winl, DMv, 2*DIv);
    wprep_kernel<<<LL*DIv*DMv/256, 256, 0, stream>>>(W_out, Wouth, Woutl, DIv, DMv);
    wxprep_kernel<<<LL*64*DIv/256, 256, 0, stream>>>(W_xproj, WxTh, WxTl);

    // --- embed ---
    embed_h1_kernel<<<NTOK, 256, 0, stream>>>(xc, yc, xt, yt, We1, be1, znh, znl);
    gemm_mfma<128,64,2,2,false,true><<<dim3(DMv/64, NTOK/128), 256, 0, stream>>>(
        znh, znl, DMv, We2h, We2l, z, be2, NTOK, DMv, DMv);

    for (int l = 0; l < LL; l++) {
        zn_prep_kernel<<<NTOK/4, 256, 0, stream>>>(z, norm_w + l*DMv, znh, znl);

        // ug = rmsnorm(z) @ W_in
        gemm_mfma<128,128,2,2,false,false><<<dim3(2*DIv/128, NTOK/128), 256, 0, stream>>>(
            znh, znl, DMv, Winh + (long)l*2*DIv*DMv, Winl + (long)l*2*DIv*DMv,
            ug, nullptr, NTOK, 2*DIv, DMv);

        conv_silu_kernel<<<NTOK*DIv/4/256, 256, 0, stream>>>(
            ug, W_conv + l*DIv*KK, b_conv + l*DIv, uc, uch, ucl);

        // dblT[64][NTOK] = WxT[l] @ ucT
        gemm_mfma<64,128,1,4,false,false><<<dim3(NTOK/128, 1), 256, 0, stream>>>(
            WxTh + (long)l*64*DIv, WxTl + (long)l*64*DIv, DIv,
            uch, ucl, dblT, nullptr, 64, NTOK, DIv);

        scanA_kernel<<<dim3(2, CCH, BB), 256, 0, stream>>>(
            dblT, uc, A_log + (long)l*DIv*DSv, W_dt + (long)l*DTRv*DIv,
            b_dt + l*DIv, Pbuf, hfin);

        scanB_kernel<<<BB*DIv*DSv/256, 256, 0, stream>>>(Pbuf, hfin);

        scanC_gate_kernel<<<dim3(2, CCH, BB), 256, 0, stream>>>(
            dblT, uc, A_log + (long)l*DIv*DSv, W_dt + (long)l*DTRv*DIv,
            b_dt + l*DIv, Pbuf, ug, Dp + l*DIv);

        // z += yg @ W_out   (yg = split-bf16 in ug rows, stride 2048 ushorts)
        gemm_mfma<128,64,2,2,true,false><<<dim3(DMv/64, NTOK/128), 256, 0, stream>>>(
            (ushort*)ug, (ushort*)ug + DIv, 4*DIv,
            Wouth + (long)l*DMv*DIv, Woutl + (long)l*DMv*DIv,
            z, nullptr, NTOK, DMv, DIv);
    }
}

// Round 6
// 649.407 us; speedup vs baseline: 1.9397x; 1.0881x over previous
//
#include <hip/hip_runtime.h>
#include <hip/hip_bf16.h>

// Problem constants
#define BB 4
#define NCC 1792
#define NTT 256
#define NN 2048        // NCC + NTT
#define DMv 256
#define DIv 512
#define DSv 16
#define DTRv 16
#define KK 4
#define LL 4
#define NTOK (BB*NN)   // 8192

#define CCH 128        // chunks for scan
#define CL  16         // chunk length = NN/CCH

#define LOG2E 1.44269504088896f

typedef short s16x8 __attribute__((ext_vector_type(8)));
typedef float f32x4 __attribute__((ext_vector_type(4)));

__device__ __forceinline__ float fast_rcp(float x) {
    return __builtin_amdgcn_rcpf(x);
}
__device__ __forceinline__ float silu_fast(float x) {
    return x * fast_rcp(1.f + __expf(-x));
}
__device__ __forceinline__ float softplus_fast(float x) {
    return fmaxf(x, 0.f) + __logf(1.f + __expf(-fabsf(x)));
}

// bf16 split helpers (round-to-nearest-even)
__device__ __forceinline__ ushort f2bf(float x) {
    uint u = __float_as_uint(x);
    u += 0x7fffu + ((u >> 16) & 1u);
    return (ushort)(u >> 16);
}
__device__ __forceinline__ float bf2f(ushort h) {
    return __uint_as_float(((uint)h) << 16);
}
__device__ __forceinline__ void split_bf(float x, ushort& hi, ushort& lo) {
    hi = f2bf(x);
    lo = f2bf(x - bf2f(hi));
}

// ---------------------------------------------------------------------------
// Weight prep: W [nl][K][N] fp32 -> th/tl [nl][N][K] bf16 (hi/lo)
// ---------------------------------------------------------------------------
__global__ __launch_bounds__(256) void wprep_kernel(
    const float* __restrict__ W, ushort* __restrict__ th, ushort* __restrict__ tl,
    int K, int N)
{
    int idx = blockIdx.x*256 + threadIdx.x;
    int perL = N*K;
    int l = idx / perL, r = idx - l*perL;
    int n = r / K, k = r - n*K;
    float v = W[(long)l*perL + (long)k*N + n];
    ushort hi, lo; split_bf(v, hi, lo);
    th[idx] = hi; tl[idx] = lo;
}

// ---------------------------------------------------------------------------
// Wx prep: W_xproj (L,512,48) -> WxT (L,64,512) bf16 hi/lo, rows 48..63 zero
// ---------------------------------------------------------------------------
__global__ __launch_bounds__(256) void wxprep_kernel(
    const float* __restrict__ Wx, ushort* __restrict__ th, ushort* __restrict__ tl)
{
    int idx = blockIdx.x*256 + threadIdx.x;   // L*64*512
    int l = idx >> 15;
    int r = idx & 32767;
    int o = r >> 9, k = r & 511;
    float v = (o < 48) ? Wx[((long)l*DIv + k)*48 + o] : 0.f;
    ushort hi, lo; split_bf(v, hi, lo);
    th[idx] = hi; tl[idx] = lo;
}

// ---------------------------------------------------------------------------
// A2 prep: A2buf = -exp(A_log)*log2(e), over all layers
// ---------------------------------------------------------------------------
__global__ __launch_bounds__(256) void a2_prep_kernel(
    const float* __restrict__ Alog, float* __restrict__ A2buf)
{
    int idx = blockIdx.x*256 + threadIdx.x;  // LL*DIv*DSv
    A2buf[idx] = -expf(Alog[idx]) * LOG2E;
}

// ---------------------------------------------------------------------------
// Embed phase 1: h1 = relu(x*We1[0,:] + yprev*We1[1,:] + be1), split to bf16
// ---------------------------------------------------------------------------
__global__ __launch_bounds__(256) void embed_h1_kernel(
    const float* __restrict__ xc, const float* __restrict__ yc,
    const float* __restrict__ xt, const float* __restrict__ yt,
    const float* __restrict__ We1, const float* __restrict__ be1,
    ushort* __restrict__ h1h, ushort* __restrict__ h1l)
{
    int token = blockIdx.x;
    int b = token >> 11, t = token & (NN - 1);
    int d = threadIdx.x;

    float xv = (t < NCC) ? xc[b*NCC + t] : xt[b*NTT + (t - NCC)];
    float yp = 0.f;
    if (t > 0) {
        int tp = t - 1;
        yp = (tp < NCC) ? yc[b*NCC + tp] : yt[b*NTT + (tp - NCC)];
    }
    float h = fmaxf(fmaf(xv, We1[d], fmaf(yp, We1[DMv + d], be1[d])), 0.f);
    ushort hi, lo; split_bf(h, hi, lo);
    h1h[(long)token*DMv + d] = hi;
    h1l[(long)token*DMv + d] = lo;
}

// ---------------------------------------------------------------------------
// zn_prep: fused rmsnorm -> split bf16. 4 tokens per 256-thread block.
// ---------------------------------------------------------------------------
__global__ __launch_bounds__(256) void zn_prep_kernel(
    const float* __restrict__ z, const float* __restrict__ nw,
    ushort* __restrict__ znh, ushort* __restrict__ znl)
{
    int tid = threadIdx.x;
    int token = blockIdx.x*4 + (tid >> 6);
    int lane = tid & 63;
    float4 v = *(const float4*)&z[(long)token*DMv + lane*4];
    float ss = v.x*v.x + v.y*v.y + v.z*v.z + v.w*v.w;
    #pragma unroll
    for (int m = 32; m >= 1; m >>= 1) ss += __shfl_xor(ss, m, 64);
    float rinv = rsqrtf(ss * (1.f/DMv) + 1e-5f);
    float4 w = *(const float4*)&nw[lane*4];
    float a0 = v.x*rinv*w.x, a1 = v.y*rinv*w.y, a2 = v.z*rinv*w.z, a3 = v.w*rinv*w.w;
    ushort h0,l0,h1,l1,h2,l2,h3,l3;
    split_bf(a0,h0,l0); split_bf(a1,h1,l1); split_bf(a2,h2,l2); split_bf(a3,h3,l3);
    ushort4 hv = {h0,h1,h2,h3}, lv = {l0,l1,l2,l3};
    *(ushort4*)&znh[(long)token*DMv + lane*4] = hv;
    *(ushort4*)&znl[(long)token*DMv + lane*4] = lv;
}

// ---------------------------------------------------------------------------
// Split-bf16 MFMA GEMM: C[M,N] (+=C if RES, +bias if BIAS) = A @ B^T
// ---------------------------------------------------------------------------
template<int BM, int BN, int WM, int WN, bool RES, bool BIAS>
__global__ __launch_bounds__(256) void gemm_mfma(
    const ushort* __restrict__ Ah, const ushort* __restrict__ Al, int lda,
    const ushort* __restrict__ Bh, const ushort* __restrict__ Bl,
    float* __restrict__ C, const float* __restrict__ bias, int M, int N, int K)
{
    constexpr int BK = 32, PAD = 40;
    constexpr int MF = BM/WM/16, NF = BN/WN/16;
    constexpr int AIT = BM*BK/8/256;
    constexpr int BIT = BN*BK/8/256;
    static_assert(WM*WN == 4, "4 waves");

    __shared__ ushort As_h[BM*PAD], As_l[BM*PAD];
    __shared__ ushort Bs_h[BN*PAD], Bs_l[BN*PAD];

    int tid = threadIdx.x;
    int lane = tid & 63, wid = tid >> 6;
    int wm = wid / WN, wn = wid % WN;
    int bm0 = blockIdx.y * BM, bn0 = blockIdx.x * BN;

    int fr = lane & 15;
    int fko = (lane >> 4) * 8;

    f32x4 acc[MF][NF];
    #pragma unroll
    for (int i = 0; i < MF; i++)
        #pragma unroll
        for (int j = 0; j < NF; j++) acc[i][j] = (f32x4){0.f,0.f,0.f,0.f};

    s16x8 rAh[AIT], rAl[AIT], rBh[BIT], rBl[BIT];

    auto loadG = [&](int s) {
        #pragma unroll
        for (int i = 0; i < AIT; i++) {
            int id = tid + i*256; int r = id >> 2, c = (id & 3)*8;
            long g = (long)(bm0 + r)*lda + s*BK + c;
            rAh[i] = *(const s16x8*)(Ah + g);
            rAl[i] = *(const s16x8*)(Al + g);
        }
        #pragma unroll
        for (int i = 0; i < BIT; i++) {
            int id = tid + i*256; int r = id >> 2, c = (id & 3)*8;
            long g = (long)(bn0 + r)*K + s*BK + c;
            rBh[i] = *(const s16x8*)(Bh + g);
            rBl[i] = *(const s16x8*)(Bl + g);
        }
    };

    loadG(0);
    int nstep = K / BK;
    for (int s = 0;; s++) {
        #pragma unroll
        for (int i = 0; i < AIT; i++) {
            int id = tid + i*256; int r = id >> 2, c = (id & 3)*8;
            *(s16x8*)&As_h[r*PAD + c] = rAh[i];
            *(s16x8*)&As_l[r*PAD + c] = rAl[i];
        }
        #pragma unroll
        for (int i = 0; i < BIT; i++) {
            int id = tid + i*256; int r = id >> 2, c = (id & 3)*8;
            *(s16x8*)&Bs_h[r*PAD + c] = rBh[i];
            *(s16x8*)&Bs_l[r*PAD + c] = rBl[i];
        }
        __syncthreads();
        if (s + 1 < nstep) loadG(s + 1);

        s16x8 ah[MF], al[MF], bh[NF], bl[NF];
        #pragma unroll
        for (int f = 0; f < MF; f++) {
            int r = (wm*MF + f)*16 + fr;
            ah[f] = *(const s16x8*)&As_h[r*PAD + fko];
            al[f] = *(const s16x8*)&As_l[r*PAD + fko];
        }
        #pragma unroll
        for (int f = 0; f < NF; f++) {
            int r = (wn*NF + f)*16 + fr;
            bh[f] = *(const s16x8*)&Bs_h[r*PAD + fko];
            bl[f] = *(const s16x8*)&Bs_l[r*PAD + fko];
        }
        #pragma unroll
        for (int mf = 0; mf < MF; mf++)
            #pragma unroll
            for (int nf = 0; nf < NF; nf++) {
                acc[mf][nf] = __builtin_amdgcn_mfma_f32_16x16x32_bf16(ah[mf], bh[nf], acc[mf][nf], 0, 0, 0);
                acc[mf][nf] = __builtin_amdgcn_mfma_f32_16x16x32_bf16(ah[mf], bl[nf], acc[mf][nf], 0, 0, 0);
                acc[mf][nf] = __builtin_amdgcn_mfma_f32_16x16x32_bf16(al[mf], bh[nf], acc[mf][nf], 0, 0, 0);
            }
        if (s + 1 >= nstep) break;
        __syncthreads();
    }

    #pragma unroll
    for (int mf = 0; mf < MF; mf++) {
        #pragma unroll
        for (int nf = 0; nf < NF; nf++) {
            int row0 = bm0 + (wm*MF + mf)*16 + (lane >> 4)*4;
            int col  = bn0 + (wn*NF + nf)*16 + fr;
            float bv = BIAS ? bias[col] : 0.f;
            #pragma unroll
            for (int j = 0; j < 4; j++) {
                long off = (long)(row0 + j)*N + col;
                float v = acc[mf][nf][j] + bv;
                if (RES) v += C[off];
                C[off] = v;
            }
        }
    }
}

// ---------------------------------------------------------------------------
// Depthwise causal conv(K=4)+bias+SiLU: f32 out + split-bf16 out
// ---------------------------------------------------------------------------
__global__ __launch_bounds__(256) void conv_silu_kernel(
    const float* __restrict__ ug, const float* __restrict__ Wc,
    const float* __restrict__ bcv, float* __restrict__ uc,
    ushort* __restrict__ uch, ushort* __restrict__ ucl)
{
    int idx = blockIdx.x*256 + threadIdx.x;       // NTOK * DIv/4
    int di = (idx & (DIv/4 - 1)) * 4;
    int token = idx >> 7;
    int t = token & (NN - 1);

    float4 w0 = *(const float4*)&Wc[(di+0)*KK];
    float4 w1 = *(const float4*)&Wc[(di+1)*KK];
    float4 w2 = *(const float4*)&Wc[(di+2)*KK];
    float4 w3 = *(const float4*)&Wc[(di+3)*KK];
    float4 acc = *(const float4*)&bcv[di];

    float4 u;
    if (t >= 3) {
        u = *(const float4*)&ug[((long)(token-3) << 10) + di];
        acc.x = fmaf(u.x, w0.x, acc.x); acc.y = fmaf(u.y, w1.x, acc.y);
        acc.z = fmaf(u.z, w2.x, acc.z); acc.w = fmaf(u.w, w3.x, acc.w);
    }
    if (t >= 2) {
        u = *(const float4*)&ug[((long)(token-2) << 10) + di];
        acc.x = fmaf(u.x, w0.y, acc.x); acc.y = fmaf(u.y, w1.y, acc.y);
        acc.z = fmaf(u.z, w2.y, acc.z); acc.w = fmaf(u.w, w3.y, acc.w);
    }
    if (t >= 1) {
        u = *(const float4*)&ug[((long)(token-1) << 10) + di];
        acc.x = fmaf(u.x, w0.z, acc.x); acc.y = fmaf(u.y, w1.z, acc.y);
        acc.z = fmaf(u.z, w2.z, acc.z); acc.w = fmaf(u.w, w3.z, acc.w);
    }
    u = *(const float4*)&ug[((long)token << 10) + di];
    acc.x = fmaf(u.x, w0.w, acc.x); acc.y = fmaf(u.y, w1.w, acc.y);
    acc.z = fmaf(u.z, w2.w, acc.z); acc.w = fmaf(u.w, w3.w, acc.w);

    acc.x = silu_fast(acc.x); acc.y = silu_fast(acc.y);
    acc.z = silu_fast(acc.z); acc.w = silu_fast(acc.w);
    *(float4*)&uc[(long)token*DIv + di] = acc;

    ushort h0,l0,h1,l1,h2,l2,h3,l3;
    split_bf(acc.x,h0,l0); split_bf(acc.y,h1,l1);
    split_bf(acc.z,h2,l2); split_bf(acc.w,h3,l3);
    ushort4 hv = {h0,h1,h2,h3}, lv = {l0,l1,l2,l3};
    *(ushort4*)&uch[(long)token*DIv + di] = hv;
    *(ushort4*)&ucl[(long)token*DIv + di] = lv;
}

// ---------------------------------------------------------------------------
// delta[token][di] = softplus( sum_k dblT[k][token]*Wdt[k][di] + bdt[di] )
// block = 2 tokens x 128 threads (4 chans each)
// ---------------------------------------------------------------------------
__global__ __launch_bounds__(256) void delta_kernel(
    const float* __restrict__ dblT, const float* __restrict__ Wdt,
    const float* __restrict__ bdt, float* __restrict__ delta)
{
    int tid = threadIdx.x;
    int token0 = blockIdx.x*2;
    __shared__ float dts[2][DTRv];
    if (tid < 32) {
        int h = tid >> 4, s = tid & 15;
        dts[h][s] = dblT[(long)s*NTOK + token0 + h];
    }
    __syncthreads();
    int h = tid >> 7;
    int di = (tid & 127) * 4;
    int token = token0 + h;
    float4 acc = *(const float4*)&bdt[di];
    #pragma unroll
    for (int k = 0; k < DTRv; k++) {
        float4 w = *(const float4*)&Wdt[k*DIv + di];
        float dv = dts[h][k];
        acc.x = fmaf(dv, w.x, acc.x); acc.y = fmaf(dv, w.y, acc.y);
        acc.z = fmaf(dv, w.z, acc.z); acc.w = fmaf(dv, w.w, acc.w);
    }
    acc.x = softplus_fast(acc.x); acc.y = softplus_fast(acc.y);
    acc.z = softplus_fast(acc.z); acc.w = softplus_fast(acc.w);
    *(float4*)&delta[(long)token*DIv + di] = acc;
}

// ---------------------------------------------------------------------------
// Scan pass A: per-chunk local scan (h=0) -> decay product P, final h
// P[s] = exp2(A2[s] * sum_tt delta)
// ---------------------------------------------------------------------------
__global__ __launch_bounds__(256) void scanA_kernel(
    const float* __restrict__ dblT, const float* __restrict__ uc,
    const float* __restrict__ delta, const float* __restrict__ A2p,
    float* __restrict__ Pbuf, float* __restrict__ hfin)
{
    int half = blockIdx.x, c = blockIdx.y, b = blockIdx.z;
    int di = half*256 + threadIdx.x;

    float A2[DSv], h[DSv];
    #pragma unroll
    for (int s4 = 0; s4 < DSv; s4 += 4) {
        float4 av = *(const float4*)&A2p[di*DSv + s4];
        A2[s4]=av.x; A2[s4+1]=av.y; A2[s4+2]=av.z; A2[s4+3]=av.w;
        h[s4]=0.f; h[s4+1]=0.f; h[s4+2]=0.f; h[s4+3]=0.f;
    }

    __shared__ float Bsh[CL][DSv+1];
    int t0 = c * CL;
    {
        int i = threadIdx.x;          // 256 == CL*DSv
        int s = i >> 4, tt = i & 15;
        Bsh[tt][s] = dblT[(long)(DTRv + s)*NTOK + (long)b*NN + t0 + tt];
    }
    __syncthreads();

    float d_r[CL], u_r[CL];
    #pragma unroll
    for (int tt = 0; tt < CL; tt++) {
        long token = (long)b*NN + t0 + tt;
        d_r[tt] = delta[token*DIv + di];
        u_r[tt] = uc[token*DIv + di];
    }

    float dsum = 0.f;
    #pragma unroll
    for (int tt = 0; tt < CL; tt++) {
        float d = d_r[tt];
        float du = d * u_r[tt];
        dsum += d;
        #pragma unroll
        for (int s = 0; s < DSv; s++) {
            float a = exp2f(d * A2[s]);
            h[s] = fmaf(a, h[s], du * Bsh[tt][s]);
        }
    }
    long base = (((long)c*BB + b)*DIv + di)*DSv;
    #pragma unroll
    for (int s = 0; s < DSv; s++) {
        Pbuf[base+s] = exp2f(A2[s] * dsum);
        hfin[base+s] = h[s];
    }
}

// ---------------------------------------------------------------------------
// Scan pass B: sequential over chunks; Pbuf overwritten with chunk-initial H
// ---------------------------------------------------------------------------
__global__ __launch_bounds__(256) void scanB_kernel(
    float* __restrict__ Pbuf, const float* __restrict__ hfin)
{
    int id = blockIdx.x * 256 + threadIdx.x;  // (b*512+di)*16+s
    float H = 0.f;
    for (int c = 0; c < CCH; c++) {
        long idx = (long)c * (BB*DIv*DSv) + id;
        float p  = Pbuf[idx];
        float hf = hfin[idx];
        Pbuf[idx] = H;               // becomes Hinit
        H = fmaf(p, H, hf);
    }
}

// ---------------------------------------------------------------------------
// Scan pass C + gate: yg = (y + D*u)*silu(gate), written as split-bf16
// into the (dead) u-half of ug rows: [512 hi | 512 lo] ushorts per token.
// ---------------------------------------------------------------------------
__global__ __launch_bounds__(256) void scanC_gate_kernel(
    const float* __restrict__ dblT, const float* __restrict__ uc,
    const float* __restrict__ delta, const float* __restrict__ A2p,
    const float* __restrict__ Hinit, float* __restrict__ ug,
    const float* __restrict__ Dp)
{
    int half = blockIdx.x, c = blockIdx.y, b = blockIdx.z;
    int di = half*256 + threadIdx.x;

    float A2[DSv], h[DSv];
    long base = (((long)c*BB + b)*DIv + di)*DSv;
    #pragma unroll
    for (int s4 = 0; s4 < DSv; s4 += 4) {
        float4 av = *(const float4*)&A2p[di*DSv + s4];
        A2[s4]=av.x; A2[s4+1]=av.y; A2[s4+2]=av.z; A2[s4+3]=av.w;
        float4 hv = *(const float4*)&Hinit[base + s4];
        h[s4]=hv.x; h[s4+1]=hv.y; h[s4+2]=hv.z; h[s4+3]=hv.w;
    }
    float Dv = Dp[di];

    __shared__ float Bsh[CL][DSv+1];
    __shared__ float Csh[CL][DSv+1];
    int t0 = c * CL;
    {
        int i = threadIdx.x;          // 256 == CL*DSv
        int s = i >> 4, tt = i & 15;
        long gb = (long)b*NN + t0 + tt;
        Bsh[tt][s] = dblT[(long)(DTRv + s)*NTOK + gb];
        Csh[tt][s] = dblT[(long)(DTRv + DSv + s)*NTOK + gb];
    }
    __syncthreads();

    float d_r[CL], u_r[CL], g_r[CL];
    #pragma unroll
    for (int tt = 0; tt < CL; tt++) {
        long token = (long)b*NN + t0 + tt;
        d_r[tt] = delta[token*DIv + di];
        u_r[tt] = uc[token*DIv + di];
        g_r[tt] = ug[((long)token << 10) + DIv + di];
    }

    #pragma unroll
    for (int tt = 0; tt < CL; tt++) {
        float d = d_r[tt], ucv = u_r[tt];
        float du = d * ucv;
        float y0 = 0.f, y1 = 0.f;
        #pragma unroll
        for (int s = 0; s < DSv; s += 2) {
            float a0 = exp2f(d * A2[s]);
            float a1 = exp2f(d * A2[s+1]);
            h[s]   = fmaf(a0, h[s],   du * Bsh[tt][s]);
            h[s+1] = fmaf(a1, h[s+1], du * Bsh[tt][s+1]);
            y0 = fmaf(h[s],   Csh[tt][s],   y0);
            y1 = fmaf(h[s+1], Csh[tt][s+1], y1);
        }
        float ygv = fmaf(Dv, ucv, y0 + y1) * silu_fast(g_r[tt]);
        ushort hi, lo; split_bf(ygv, hi, lo);
        long token = (long)b*NN + t0 + tt;
        ushort* ygrow = (ushort*)(ug + ((long)token << 10));
        ygrow[di] = hi;
        ygrow[DIv + di] = lo;
    }
}

// ---------------------------------------------------------------------------
extern "C" void kernel_launch(void* const* d_in, const int* in_sizes, int n_in,
                              void* d_out, int out_size, void* d_ws, size_t ws_size,
                              hipStream_t stream)
{
    const float* xc     = (const float*)d_in[0];
    const float* yc     = (const float*)d_in[1];
    const float* xt     = (const float*)d_in[2];
    const float* yt     = (const float*)d_in[3];
    const float* We1    = (const float*)d_in[4];
    const float* be1    = (const float*)d_in[5];
    const float* We2    = (const float*)d_in[6];
    const float* be2    = (const float*)d_in[7];
    const float* norm_w = (const float*)d_in[8];
    const float* W_in   = (const float*)d_in[9];
    const float* W_conv = (const float*)d_in[10];
    const float* b_conv = (const float*)d_in[11];
    const float* W_xproj= (const float*)d_in[12];
    const float* W_dt   = (const float*)d_in[13];
    const float* b_dt   = (const float*)d_in[14];
    const float* A_log  = (const float*)d_in[15];
    const float* Dp     = (const float*)d_in[16];
    const float* W_out  = (const float*)d_in[17];

    float* z  = (float*)d_out;               // (B,N,DM) in place
    float* ws = (float*)d_ws;

    float* ug    = ws;                        // NTOK*1024 f32 (u|gate; u-half becomes yg bf16)
    float* uc    = ug    + (long)NTOK*2*DIv;  // NTOK*512 f32
    float* delta = uc    + (long)NTOK*DIv;    // NTOK*512 f32
    float* dblT  = delta + (long)NTOK*DIv;    // 64*NTOK f32 [dt|B|C|0] transposed
    float* Pbuf  = dblT  + (long)64*NTOK;     // CCH*BB*DIv*DSv (becomes Hinit)
    float* hfin  = Pbuf  + (long)CCH*BB*DIv*DSv;
    float* A2buf = hfin  + (long)CCH*BB*DIv*DSv;   // LL*DIv*DSv

    ushort* uch  = (ushort*)(A2buf + (long)LL*DIv*DSv); // NTOK*512
    ushort* ucl  = uch + (long)NTOK*DIv;
    ushort* znh  = ucl + (long)NTOK*DIv;                   // NTOK*256
    ushort* znl  = znh + (long)NTOK*DMv;
    ushort* We2h = znl + (long)NTOK*DMv;                   // 256*256
    ushort* We2l = We2h + DMv*DMv;
    ushort* Winh = We2l + DMv*DMv;                         // LL*1024*256
    ushort* Winl = Winh + (long)LL*2*DIv*DMv;
    ushort* Wouth= Winl + (long)LL*2*DIv*DMv;              // LL*256*512
    ushort* Woutl= Wouth + (long)LL*DMv*DIv;
    ushort* WxTh = Woutl + (long)LL*DMv*DIv;               // LL*64*512
    ushort* WxTl = WxTh + (long)LL*64*DIv;

    // --- one-time weight prep (batched over layers) ---
    wprep_kernel<<<DMv*DMv/256, 256, 0, stream>>>(We2, We2h, We2l, DMv, DMv);
    wprep_kernel<<<LL*DMv*2*DIv/256, 256, 0, stream>>>(W_in, Winh, Winl, DMv, 2*DIv);
    wprep_kernel<<<LL*DIv*DMv/256, 256, 0, stream>>>(W_out, Wouth, Woutl, DIv, DMv);
    wxprep_kernel<<<LL*64*DIv/256, 256, 0, stream>>>(W_xproj, WxTh, WxTl);
    a2_prep_kernel<<<LL*DIv*DSv/256, 256, 0, stream>>>(A_log, A2buf);

    // --- embed ---
    embed_h1_kernel<<<NTOK, 256, 0, stream>>>(xc, yc, xt, yt, We1, be1, znh, znl);
    gemm_mfma<128,64,2,2,false,true><<<dim3(DMv/64, NTOK/128), 256, 0, stream>>>(
        znh, znl, DMv, We2h, We2l, z, be2, NTOK, DMv, DMv);

    for (int l = 0; l < LL; l++) {
        zn_prep_kernel<<<NTOK/4, 256, 0, stream>>>(z, norm_w + l*DMv, znh, znl);

        // ug = rmsnorm(z) @ W_in
        gemm_mfma<128,128,2,2,false,false><<<dim3(2*DIv/128, NTOK/128), 256, 0, stream>>>(
            znh, znl, DMv, Winh + (long)l*2*DIv*DMv, Winl + (long)l*2*DIv*DMv,
            ug, nullptr, NTOK, 2*DIv, DMv);

        conv_silu_kernel<<<NTOK*DIv/4/256, 256, 0, stream>>>(
            ug, W_conv + l*DIv*KK, b_conv + l*DIv, uc, uch, ucl);

        // dblT[64][NTOK] = WxT[l] @ ucT
        gemm_mfma<64,64,1,4,false,false><<<dim3(NTOK/64, 1), 256, 0, stream>>>(
            WxTh + (long)l*64*DIv, WxTl + (long)l*64*DIv, DIv,
            uch, ucl, dblT, nullptr, 64, NTOK, DIv);

        delta_kernel<<<NTOK/2, 256, 0, stream>>>(
            dblT, W_dt + (long)l*DTRv*DIv, b_dt + l*DIv, delta);

        scanA_kernel<<<dim3(2, CCH, BB), 256, 0, stream>>>(
            dblT, uc, delta, A2buf + (long)l*DIv*DSv, Pbuf, hfin);

        scanB_kernel<<<BB*DIv*DSv/256, 256, 0, stream>>>(Pbuf, hfin);

        scanC_gate_kernel<<<dim3(2, CCH, BB), 256, 0, stream>>>(
            dblT, uc, delta, A2buf + (long)l*DIv*DSv, Pbuf, ug, Dp + l*DIv);

        // z += yg @ W_out   (yg = split-bf16 in ug rows, stride 2048 ushorts)
        gemm_mfma<128,64,2,2,true,false><<<dim3(DMv/64, NTOK/128), 256, 0, stream>>>(
            (ushort*)ug, (ushort*)ug + DIv, 4*DIv,
            Wouth + (long)l*DMv*DIv, Woutl + (long)l*DMv*DIv,
            z, nullptr, NTOK, DMv, DIv);
    }
}